// Round 14
// baseline (219.379 us; speedup 1.0000x reference)
//
#include <hip/hip_runtime.h>

// MultiHeadAttention: x@Wq/Wk/Wv -> causal flash attn -> @Wo
// B=2 S=2048 H=16 D=64 HIDDEN=1024. All MFMA bf16 16x16x32, f32 accum.
//
// R13 changes vs R12:
//  - REVERT gemm_qkv to R11 (R12 dbuf was null: barrier vmcnt(0) drain
//    defeats intra-iteration prefetch; compute phase < load latency).
//  - attn_fwd: single-buffered K/V LDS (64->32KB => 4 blocks/CU, 32/32 wave
//    slots) with two barriers per tile-pair (compute | bar | overwrite | bar).
//    Register prefetch LOADKV(t+1) still hides load latency under the
//    ~1500cyc compute phase. launch_bounds (512,8), VGPR<=64.
//
// Workspace map (64 MiB), with region reuse:
//   [0)         PO bf16 partial O: 1280 slices x 128 rows x 64 d (21 MiB)
//   [25165824)  ML f32: 1280 slices x 128 rows x {m,l}  (1.31 MiB)
//   [31457280)  woT (live until gemm_out)   [wT block: 25165824 + z*2MiB]
//   [33554432)  Qb  bf16 [4096][1024]  (pre-scaled by 0.125*log2(e))
//   [41943040)  Kb  bf16 [4096][1024]
//   [50331648)  VTb bf16 [b][h][d][s] = [2][16][64][2048]
//   [58720256)  Ob  bf16 [4096][1024]
//   NOTE: ML aliases wqT/wkT which are DEAD after gemm_qkv completes.

using u16 = unsigned short;
typedef __bf16 bf16x8 __attribute__((ext_vector_type(8)));
typedef short  s16x8  __attribute__((ext_vector_type(8)));
typedef float  f32x4  __attribute__((ext_vector_type(4)));

#define SEQ   2048
#define QSC   0.18033688f   /* 0.125 * log2(e) */

__device__ __forceinline__ u16 to_bf16(float f) {
  return __builtin_bit_cast(u16, (__bf16)f);
}
__device__ __forceinline__ float from_bf16(u16 v) {
  return __builtin_bit_cast(float, ((unsigned)v) << 16);
}
__device__ __forceinline__ bf16x8 frag_cast(s16x8 v) {
  return __builtin_bit_cast(bf16x8, v);
}
__device__ __forceinline__ f32x4 mfma16(bf16x8 a, bf16x8 b, f32x4 c) {
  return __builtin_amdgcn_mfma_f32_16x16x32_bf16(a, b, c, 0, 0, 0);
}
__device__ __forceinline__ void gload_lds16(const void* g, void* l) {
  __builtin_amdgcn_global_load_lds(
      (const __attribute__((address_space(1))) void*)g,
      (__attribute__((address_space(3))) void*)l, 16, 0, 0);
}

// ---------------- weight transpose+convert: w[K][N] f32 -> wT[N][K] bf16 --
__global__ __launch_bounds__(256) void transpose_w(const float* __restrict__ wq,
                                                   const float* __restrict__ wk,
                                                   const float* __restrict__ wv,
                                                   const float* __restrict__ wo,
                                                   u16* __restrict__ wT) {
  __shared__ float tile[32][33];
  const float* src = blockIdx.z == 0 ? wq : blockIdx.z == 1 ? wk
                     : blockIdx.z == 2 ? wv : wo;
  u16* dst = wT + (size_t)blockIdx.z * 1048576;
  const int x0 = blockIdx.x * 32, y0 = blockIdx.y * 32;
  const int tx = threadIdx.x, ty = threadIdx.y;  // block (32,8)
#pragma unroll
  for (int i = 0; i < 4; ++i)
    tile[ty + i * 8][tx] = src[(size_t)(y0 + ty + i * 8) * 1024 + x0 + tx];
  __syncthreads();
#pragma unroll
  for (int i = 0; i < 4; ++i)
    dst[(size_t)(x0 + ty + i * 8) * 1024 + y0 + tx] = to_bf16(tile[tx][ty + i * 8]);
}

// ---------------- fused QKV GEMM + f32->bf16 convert (R11 version) --------
// z=0: Qb = q@wqT^T (scaled); z=1: Kb = k@wkT^T; z=2 swapped: VT = wvT@v^T.
__global__ __launch_bounds__(256) void gemm_qkv(const float* __restrict__ Xq,
                                                const float* __restrict__ Xk,
                                                const float* __restrict__ Xv,
                                                const u16* __restrict__ WT,
                                                u16* __restrict__ Qb,
                                                u16* __restrict__ Kb,
                                                u16* __restrict__ VTb) {
  __shared__ u16 As[128 * 32];
  __shared__ u16 Bs[128 * 32];
  const int z = blockIdx.z;
  const u16* Gbf;      // bf16 operand (gload_lds)
  const float* Gf32;   // f32 operand (reg-staged)
  int row0, n0;
  if (z == 2) {
    Gbf = WT + 2097152;             // A = wvT [1024][1024]
    Gf32 = Xv;                      // B = value rows (seq)
    row0 = blockIdx.y * 128;        // 8 row-blocks
    n0 = blockIdx.x * 128;          // 32 col-blocks
  } else {
    Gf32 = z ? Xk : Xq;             // A = x rows (seq)
    Gbf = WT + (size_t)z * 1048576; // B = wT
    row0 = blockIdx.x * 128;
    n0 = blockIdx.y * 128;
  }
  const int tid = threadIdx.x;
  const int w = tid >> 6, lane = tid & 63;
  const int g = lane >> 4, c = lane & 15;
  const int wr = w >> 1, wc = w & 1;

  f32x4 acc[4][4];
#pragma unroll
  for (int i = 0; i < 4; ++i)
#pragma unroll
    for (int j = 0; j < 4; ++j) acc[i][j] = (f32x4){0.f, 0.f, 0.f, 0.f};

  const int sub = lane >> 2;                       // row within 16-row chunk
  const int kq = lane & 3;                         // k-group slot
  const int ksrc = (kq ^ ((sub >> 1) & 3)) * 8;    // swizzled source k-group
  const int fsw = ((c >> 1) & 3);                  // frag-read swizzle key

  for (int kt = 0; kt < 32; ++kt) {
    const int k0 = kt * 32;
    s16x8 sreg[2];
#pragma unroll
    for (int it = 0; it < 2; ++it) {
      const int ch = w * 2 + it;
      const int row = ch * 16 + sub;
      if (z == 2) {
        gload_lds16(Gbf + (size_t)(row0 + row) * 1024 + k0 + ksrc, (char*)As + ch * 1024);
        const float4* p = (const float4*)(Gf32 + (size_t)(n0 + row) * 1024 + k0 + ksrc);
        const float4 aa = p[0], bb = p[1];
        s16x8 o;
        o[0] = (short)to_bf16(aa.x); o[1] = (short)to_bf16(aa.y);
        o[2] = (short)to_bf16(aa.z); o[3] = (short)to_bf16(aa.w);
        o[4] = (short)to_bf16(bb.x); o[5] = (short)to_bf16(bb.y);
        o[6] = (short)to_bf16(bb.z); o[7] = (short)to_bf16(bb.w);
        sreg[it] = o;
      } else {
        gload_lds16(Gbf + (size_t)(n0 + row) * 1024 + k0 + ksrc, (char*)Bs + ch * 1024);
        const float4* p = (const float4*)(Gf32 + (size_t)(row0 + row) * 1024 + k0 + ksrc);
        const float4 aa = p[0], bb = p[1];
        s16x8 o;
        o[0] = (short)to_bf16(aa.x); o[1] = (short)to_bf16(aa.y);
        o[2] = (short)to_bf16(aa.z); o[3] = (short)to_bf16(aa.w);
        o[4] = (short)to_bf16(bb.x); o[5] = (short)to_bf16(bb.y);
        o[6] = (short)to_bf16(bb.z); o[7] = (short)to_bf16(bb.w);
        sreg[it] = o;
      }
    }
    {  // write reg-staged halves to the SAME addresses gload_lds would use
      char* dstbase = (z == 2) ? (char*)Bs : (char*)As;
#pragma unroll
      for (int it = 0; it < 2; ++it)
        *(s16x8*)(dstbase + (w * 2 + it) * 1024 + lane * 16) = sreg[it];
    }
    __syncthreads();

    bf16x8 af[4], bfr[4];
#pragma unroll
    for (int mi = 0; mi < 4; ++mi)
      af[mi] = frag_cast(*(const s16x8*)((const char*)As + (wr * 64 + mi * 16 + c) * 64 + ((g ^ fsw) << 4)));
#pragma unroll
    for (int ni = 0; ni < 4; ++ni)
      bfr[ni] = frag_cast(*(const s16x8*)((const char*)Bs + (wc * 64 + ni * 16 + c) * 64 + ((g ^ fsw) << 4)));
#pragma unroll
    for (int mi = 0; mi < 4; ++mi)
#pragma unroll
      for (int ni = 0; ni < 4; ++ni)
        acc[mi][ni] = mfma16(af[mi], bfr[ni], acc[mi][ni]);
    __syncthreads();
  }

  const float sc = (z == 0) ? QSC : 1.0f;
#pragma unroll
  for (int mi = 0; mi < 4; ++mi) {
    const int rowb = row0 + wr * 64 + mi * 16 + g * 4;
#pragma unroll
    for (int ni = 0; ni < 4; ++ni) {
      const int col = n0 + wc * 64 + ni * 16 + c;
#pragma unroll
      for (int r = 0; r < 4; ++r) {
        const int row = rowb + r;
        const float v = acc[mi][ni][r] * sc;
        if (z == 2) {
          // row = h*64+d, col = b*2048+s
          const int hh = row >> 6, d = row & 63;
          const int bb = col >> 11, s = col & 2047;
          VTb[((size_t)((bb * 16 + hh) * 64 + d)) * 2048 + s] = to_bf16(v);
        } else {
          u16* C = z == 0 ? Qb : Kb;
          C[(size_t)row * 1024 + col] = to_bf16(v);
        }
      }
    }
  }
}

// ---------------- out projection GEMM: BM=64, BN=128, f32 out ------------
__global__ __launch_bounds__(256) void gemm_out(const u16* __restrict__ A,
                                                const u16* __restrict__ BT,
                                                float* __restrict__ C) {
  __shared__ u16 As[64 * 32];
  __shared__ u16 Bs[128 * 32];
  const int tid = threadIdx.x;
  const int w = tid >> 6, lane = tid & 63;
  const int g = lane >> 4, c = lane & 15;
  const int wr = w >> 1, wc = w & 1;
  const int row0 = blockIdx.x * 64;
  const int n0 = blockIdx.y * 128;

  f32x4 acc[2][4];
#pragma unroll
  for (int i = 0; i < 2; ++i)
#pragma unroll
    for (int j = 0; j < 4; ++j) acc[i][j] = (f32x4){0.f, 0.f, 0.f, 0.f};

  const int sub = lane >> 2;
  const int kq = lane & 3;
  const int ksrc = (kq ^ ((sub >> 1) & 3)) * 8;
  const int fsw = ((c >> 1) & 3);

  for (int kt = 0; kt < 32; ++kt) {
    const int k0 = kt * 32;
    {
      const int row = w * 16 + sub;
      gload_lds16(A + (size_t)(row0 + row) * 1024 + k0 + ksrc, (char*)As + w * 1024);
    }
#pragma unroll
    for (int it = 0; it < 2; ++it) {
      const int ch = w * 2 + it;
      const int row = ch * 16 + sub;
      gload_lds16(BT + (size_t)(n0 + row) * 1024 + k0 + ksrc, (char*)Bs + ch * 1024);
    }
    __syncthreads();

    bf16x8 af[2], bfr[4];
#pragma unroll
    for (int mi = 0; mi < 2; ++mi)
      af[mi] = frag_cast(*(const s16x8*)((const char*)As + (wr * 32 + mi * 16 + c) * 64 + ((g ^ fsw) << 4)));
#pragma unroll
    for (int ni = 0; ni < 4; ++ni)
      bfr[ni] = frag_cast(*(const s16x8*)((const char*)Bs + (wc * 64 + ni * 16 + c) * 64 + ((g ^ fsw) << 4)));
#pragma unroll
    for (int mi = 0; mi < 2; ++mi)
#pragma unroll
      for (int ni = 0; ni < 4; ++ni)
        acc[mi][ni] = mfma16(af[mi], bfr[ni], acc[mi][ni]);
    __syncthreads();
  }

#pragma unroll
  for (int mi = 0; mi < 2; ++mi) {
    const int rowb = row0 + wr * 32 + mi * 16 + g * 4;
#pragma unroll
    for (int ni = 0; ni < 4; ++ni) {
      const int col = n0 + wc * 64 + ni * 16 + c;
#pragma unroll
      for (int r = 0; r < 4; ++r)
        C[(size_t)(rowb + r) * 1024 + col] = acc[mi][ni][r];
    }
  }
}

// ---------------- causal flash attention, 8-wave, KVBLK=128 ---------------
// Single-buffered K/V LDS (32KB => 4 blocks/CU), 2 barriers per tile-pair.
// grid (40, 32) remapped XCD-wise. Slice covers <=4 kv tile-pairs
// (ns=(x+4)>>2; 40 slices/bh). 8 waves x 16 q-rows. Permuted-K LDS slot
// (kv&0x63)|((kv&4)<<2)|((kv&0x18)>>1); QK^T C-slot (kvf,g,r) holds
// kv=32(kvf>>1)+4(kvf&1)+8g+r -> PV A-frags packed in place. l via ones-MFMA.
__global__ __launch_bounds__(512, 8) void attn_fwd(const u16* __restrict__ Qb,
                                                   const u16* __restrict__ Kb,
                                                   const u16* __restrict__ VTb,
                                                   u16* __restrict__ PO,
                                                   float* __restrict__ ML) {
  __shared__ u16 Ks[128 * 64];   // [slot][d] swizzled   (16 KB)
  __shared__ u16 VTs[64 * 128];  // [d][kv] swizzled     (16 KB)

  const int tid = threadIdx.x;
  const int w = tid >> 6, lane = tid & 63;
  const int g = lane >> 4, c = lane & 15;

  // XCD-aware remap: flat -> logical so each XCD gets 4 consecutive bh
  const int flat = blockIdx.x + 40 * blockIdx.y;
  const int logical = (flat & 7) * 160 + (flat >> 3);
  const int slice_id = logical % 40;
  const int bh = logical / 40;
  const int b = bh >> 4, h = bh & 15;

  // decode slice id -> (q-block x, slice sid); ns(x) = (x+4)>>2 over pairs
  int sid = slice_id, x = 0;
  for (; x < 16; ++x) {
    const int ns_ = (x + 4) >> 2;
    if (sid < ns_) break;
    sid -= ns_;
  }
  const int ns = (x + 4) >> 2;
  const int np = x + 1;                       // kv tile-pairs for q-block x
  const int t0 = (sid * np) / ns, t1 = ((sid + 1) * np) / ns;
  const int sg = slice_id + 40 * bh;          // global slice id
  const int q0w = x * 128 + w * 16;           // this wave's first q row

  // Q fragments (B-operand: n=q, k=d) in registers
  bf16x8 qfr[2];
#pragma unroll
  for (int ch = 0; ch < 2; ++ch)
    qfr[ch] = frag_cast(*(const s16x8*)(Qb + (size_t)(b * SEQ + q0w + c) * 1024 + h * 64 + ch * 32 + g * 8));

  s16x8 ones_s;
#pragma unroll
  for (int j = 0; j < 8; ++j) ones_s[j] = (short)0x3F80;  // bf16 1.0
  const bf16x8 onesf = frag_cast(ones_s);

  f32x4 oacc[4];
#pragma unroll
  for (int j = 0; j < 4; ++j) oacc[j] = (f32x4){0.f, 0.f, 0.f, 0.f};
  f32x4 lacc = (f32x4){0.f, 0.f, 0.f, 0.f};
  float m_run = -1e30f;

  // staging geometry
  const int srow = tid >> 3;        // K: 0..63 (+64 on 2nd pass)
  const int scol = (tid & 7) * 8;   // K col elems
  const int vd = tid >> 4;          // V: 0..31 (+32 on 2nd pass)
  const int vcol = (tid & 15) * 8;  // V col elems (kv within pair)

  s16x8 kreg[2], vreg[2];
#define LOADKV(T)                                                                              \
  {                                                                                            \
    const int kv0_ = (T)*128;                                                                  \
    _Pragma("unroll") for (int it = 0; it < 2; ++it) {                                         \
      kreg[it] = *(const s16x8*)(Kb + (size_t)(b * SEQ + kv0_ + srow + it * 64) * 1024 +       \
                                 h * 64 + scol);                                               \
      vreg[it] = *(const s16x8*)(VTb + ((size_t)(bh * 64 + vd + it * 32)) * 2048 + kv0_ +      \
                                 vcol);                                                        \
    }                                                                                          \
  }
#define WRITEKV()                                                                              \
  {                                                                                            \
    _Pragma("unroll") for (int it = 0; it < 2; ++it) {                                         \
      const int rr_ = srow + it * 64;                                                          \
      const int pr_ = (rr_ & 0x63) | ((rr_ & 4) << 2) | ((rr_ & 0x18) >> 1);                   \
      *(s16x8*)((char*)Ks + pr_ * 128 + ((scol * 2) ^ ((pr_ & 7) << 4))) = kreg[it];           \
      const int vr_ = vd + it * 32;                                                            \
      *(s16x8*)((char*)VTs + vr_ * 256 + ((vcol * 2) ^ ((vr_ & 7) << 4))) = vreg[it];          \
    }                                                                                          \
  }

  LOADKV(t0);
  WRITEKV();
  __syncthreads();

  for (int t = t0; t < t1; ++t) {
    const bool pre = (t + 1 < t1);
    if (pre) LOADKV(t + 1);          // reg prefetch; lands under compute

    const int kv0 = t * 128;
    if (!(kv0 > q0w + 15)) {         // wave has live rows in this pair
      // ---- S^T = K * Q^T over 128 kv: 8 kvf frags
      f32x4 sa[8];
#pragma unroll
      for (int i = 0; i < 8; ++i) sa[i] = (f32x4){0.f, 0.f, 0.f, 0.f};
#pragma unroll
      for (int kvf = 0; kvf < 8; ++kvf) {
        const int kr = kvf * 16 + c;
        const int rb = kr * 128, swz = (kr & 7) << 4;
#pragma unroll
        for (int ch = 0; ch < 2; ++ch) {
          const bf16x8 ak = frag_cast(*(const s16x8*)((char*)Ks + rb + ((ch * 64 + g * 16) ^ swz)));
          sa[kvf] = mfma16(ak, qfr[ch], sa[kvf]);
        }
      }

      // ---- mask (diagonal pairs only) + tile max
      float mt = -1e30f;
      if (kv0 + 127 > q0w) {         // diagonal pair: mask with permuted kv
        const int q_abs = q0w + c;
#pragma unroll
        for (int kvf = 0; kvf < 8; ++kvf) {
          const int kvb = kv0 + (kvf >> 1) * 32 + (kvf & 1) * 4 + 8 * g;
#pragma unroll
          for (int r = 0; r < 4; ++r) {
            float s = sa[kvf][r];
            if (kvb + r > q_abs) s = -30000.f;
            sa[kvf][r] = s;
            mt = fmaxf(mt, s);
          }
        }
      } else {
#pragma unroll
        for (int kvf = 0; kvf < 8; ++kvf)
#pragma unroll
          for (int r = 0; r < 4; ++r) mt = fmaxf(mt, sa[kvf][r]);
      }
      mt = fmaxf(mt, __shfl_xor(mt, 16));
      mt = fmaxf(mt, __shfl_xor(mt, 32));

      if (__any(mt > m_run + 8.f)) {   // defer-max (T13)
        const float m_new = fmaxf(m_run, mt);
        const float alpha = __builtin_amdgcn_exp2f(m_run - m_new);
        m_run = m_new;
#pragma unroll
        for (int r = 0; r < 4; ++r) {
          const float ar = __shfl(alpha, g * 4 + r);
#pragma unroll
          for (int df = 0; df < 4; ++df) oacc[df][r] *= ar;
          lacc[r] *= ar;
        }
      }

      // ---- exp2 + pack in place into PV A-fragments (4 ch of 32 kv)
      s16x8 pk[4];
#pragma unroll
      for (int kvf = 0; kvf < 8; ++kvf)
#pragma unroll
        for (int r = 0; r < 4; ++r) {
          const float p = __builtin_amdgcn_exp2f(sa[kvf][r] - m_run);
          pk[kvf >> 1][(kvf & 1) * 4 + r] = (short)to_bf16(p);
        }

      // ---- O += P*V ; l += P*1 (row-sum via MFMA, no shfl)
#pragma unroll
      for (int ch = 0; ch < 4; ++ch) {
        const bf16x8 ap = frag_cast(pk[ch]);
#pragma unroll
        for (int df = 0; df < 4; ++df) {
          const int dr = df * 16 + c;
          const bf16x8 bv = frag_cast(*(const s16x8*)((char*)VTs + dr * 256 +
                                                      ((ch * 64 + g * 16) ^ ((dr & 7) << 4))));
          oacc[df] = mfma16(ap, bv, oacc[df]);
        }
        lacc = mfma16(ap, onesf, lacc);
      }
    }

    __syncthreads();               // all waves done reading Ks/VTs
    if (pre) {
      WRITEKV();                   // overwrite with next pair
      __syncthreads();             // writes visible before next compute
    }
  }

  // epilogue: bf16 unnormalized partial O; f32 (m,l)
  const size_t pob = (size_t)sg * 8192;
#pragma unroll
  for (int r = 0; r < 4; ++r) {
    const int row = w * 16 + g * 4 + r;
#pragma unroll
    for (int df = 0; df < 4; ++df)
      PO[pob + row * 64 + df * 16 + c] = to_bf16(oacc[df][r]);
  }
  if (g == 0)
    ML[sg * 256 + (w * 16 + c) * 2 + 0] = m_run;     // m for q=c
  if (c == 0) {
#pragma unroll
    for (int r = 0; r < 4; ++r)
      ML[sg * 256 + (w * 16 + g * 4 + r) * 2 + 1] = lacc[r];  // l for q=4g+r
  }
}

// ---------------- merge split-kv partials -> bf16 Ob ----------------------
// grid (16, 32), 512 thr: x = q-block (128 rows), y = bh. row=tid/4, 16 cols.
__global__ __launch_bounds__(512) void attn_merge(const u16* __restrict__ PO,
                                                  const float* __restrict__ ML,
                                                  u16* __restrict__ Ob) {
  const int x = blockIdx.x, bh = blockIdx.y;
  const int b = bh >> 4, h = bh & 15;
  const int tid = threadIdx.x;
  const int row = tid >> 2, c0 = (tid & 3) << 4;

  int base = 0;
  for (int xp = 0; xp < x; ++xp) base += (xp + 4) >> 2;
  const int ns = (x + 4) >> 2;
  const int sg0 = base + 40 * bh;

  float m[4], l[4], a[4];
  float M = -3e38f;
  for (int i = 0; i < ns; ++i) {
    m[i] = ML[(sg0 + i) * 256 + row * 2 + 0];
    l[i] = ML[(sg0 + i) * 256 + row * 2 + 1];
    M = fmaxf(M, m[i]);
  }
  float denom = 0.f;
  for (int i = 0; i < ns; ++i) {
    a[i] = __builtin_amdgcn_exp2f(m[i] - M);
    denom += a[i] * l[i];
  }
  const float inv = 1.f / denom;

  float o[16];
#pragma unroll
  for (int j = 0; j < 16; ++j) o[j] = 0.f;
  for (int i = 0; i < ns; ++i) {
    const float s = a[i] * inv;
    const u16* p = PO + (size_t)(sg0 + i) * 8192 + row * 64 + c0;
    const s16x8 v0 = *(const s16x8*)p;
    const s16x8 v1 = *(const s16x8*)(p + 8);
#pragma unroll
    for (int j = 0; j < 8; ++j) {
      o[j] += s * from_bf16((u16)v0[j]);
      o[8 + j] += s * from_bf16((u16)v1[j]);
    }
  }

  s16x8 lo, hi;
#pragma unroll
  for (int j = 0; j < 8; ++j) {
    lo[j] = (short)to_bf16(o[j]);
    hi[j] = (short)to_bf16(o[8 + j]);
  }
  u16* dst = Ob + (size_t)(b * SEQ + x * 128 + row) * 1024 + h * 64 + c0;
  *(s16x8*)dst = lo;
  *(s16x8*)(dst + 8) = hi;
}

// --------------------------------------------------------------------------
extern "C" void kernel_launch(void* const* d_in, const int* in_sizes, int n_in,
                              void* d_out, int out_size, void* d_ws, size_t ws_size,
                              hipStream_t stream) {
  const float* query = (const float*)d_in[0];
  const float* key_ = (const float*)d_in[1];
  const float* value = (const float*)d_in[2];
  const float* w_q = (const float*)d_in[3];
  const float* w_k = (const float*)d_in[4];
  const float* w_v = (const float*)d_in[5];
  const float* w_o = (const float*)d_in[6];

  char* ws = (char*)d_ws;
  u16* PO = (u16*)(ws + 0);
  u16* wT = (u16*)(ws + 25165824);
  float* ML = (float*)(ws + 25165824);   // aliases wqT/wkT (dead post-qkv)
  u16* Qb = (u16*)(ws + 33554432);
  u16* Kb = (u16*)(ws + 41943040);
  u16* VTb = (u16*)(ws + 50331648);
  u16* Ob = (u16*)(ws + 58720256);

  transpose_w<<<dim3(32, 32, 4), dim3(32, 8), 0, stream>>>(w_q, w_k, w_v, w_o, wT);
  gemm_qkv<<<dim3(32, 8, 3), 256, 0, stream>>>(query, key_, value, wT, Qb, Kb, VTb);
  attn_fwd<<<dim3(40, 32), 512, 0, stream>>>(Qb, Kb, VTb, PO, ML);
  attn_merge<<<dim3(16, 32), 512, 0, stream>>>(PO, ML, Ob);
  gemm_out<<<dim3(64, 8), 256, 0, stream>>>(Ob, wT + 3145728, (float*)d_out);
}

// Round 15
// 132.151 us; speedup vs baseline: 1.6601x; 1.6601x over previous
//
#include <hip/hip_runtime.h>

// MultiHeadAttention: x@Wq/Wk/Wv -> causal flash attn -> @Wo
// B=2 S=2048 H=16 D=64 HIDDEN=1024. All MFMA bf16 16x16x32, f32 accum.
//
// R14 changes:
//  - REVERT attn_fwd to R8/R11 dbuf version verbatim (R13's single-buffer +
//    (512,8) forced VGPR<=64 -> spill -> 365MB scratch writes, 145us).
//  - gemm_qkv: BM=64 x BN=128 tiles (gemm_out's proven wave structure):
//    1536 blocks = 6/CU (was 768 = 3/CU, latency-starved). f32 operand
//    reg-staged+cvt (R11 pattern), weight via global_load_lds. LDS 12KB.
//
// Workspace map (64 MiB), with region reuse:
//   [0)         PO bf16 partial O: 1280 slices x 128 rows x 64 d (21 MiB)
//   [25165824)  ML f32: 1280 slices x 128 rows x {m,l}  (1.31 MiB)
//   [31457280)  woT (live until gemm_out)   [wT block: 25165824 + z*2MiB]
//   [33554432)  Qb  bf16 [4096][1024]  (pre-scaled by 0.125*log2(e))
//   [41943040)  Kb  bf16 [4096][1024]
//   [50331648)  VTb bf16 [b][h][d][s] = [2][16][64][2048]
//   [58720256)  Ob  bf16 [4096][1024]
//   NOTE: ML aliases wqT/wkT which are DEAD after gemm_qkv completes.

using u16 = unsigned short;
typedef __bf16 bf16x8 __attribute__((ext_vector_type(8)));
typedef short  s16x8  __attribute__((ext_vector_type(8)));
typedef float  f32x4  __attribute__((ext_vector_type(4)));

#define SEQ   2048
#define QSC   0.18033688f   /* 0.125 * log2(e) */

__device__ __forceinline__ u16 to_bf16(float f) {
  return __builtin_bit_cast(u16, (__bf16)f);
}
__device__ __forceinline__ float from_bf16(u16 v) {
  return __builtin_bit_cast(float, ((unsigned)v) << 16);
}
__device__ __forceinline__ bf16x8 frag_cast(s16x8 v) {
  return __builtin_bit_cast(bf16x8, v);
}
__device__ __forceinline__ f32x4 mfma16(bf16x8 a, bf16x8 b, f32x4 c) {
  return __builtin_amdgcn_mfma_f32_16x16x32_bf16(a, b, c, 0, 0, 0);
}
__device__ __forceinline__ void gload_lds16(const void* g, void* l) {
  __builtin_amdgcn_global_load_lds(
      (const __attribute__((address_space(1))) void*)g,
      (__attribute__((address_space(3))) void*)l, 16, 0, 0);
}

// ---------------- weight transpose+convert: w[K][N] f32 -> wT[N][K] bf16 --
__global__ __launch_bounds__(256) void transpose_w(const float* __restrict__ wq,
                                                   const float* __restrict__ wk,
                                                   const float* __restrict__ wv,
                                                   const float* __restrict__ wo,
                                                   u16* __restrict__ wT) {
  __shared__ float tile[32][33];
  const float* src = blockIdx.z == 0 ? wq : blockIdx.z == 1 ? wk
                     : blockIdx.z == 2 ? wv : wo;
  u16* dst = wT + (size_t)blockIdx.z * 1048576;
  const int x0 = blockIdx.x * 32, y0 = blockIdx.y * 32;
  const int tx = threadIdx.x, ty = threadIdx.y;  // block (32,8)
#pragma unroll
  for (int i = 0; i < 4; ++i)
    tile[ty + i * 8][tx] = src[(size_t)(y0 + ty + i * 8) * 1024 + x0 + tx];
  __syncthreads();
#pragma unroll
  for (int i = 0; i < 4; ++i)
    dst[(size_t)(x0 + ty + i * 8) * 1024 + y0 + tx] = to_bf16(tile[tx][ty + i * 8]);
}

// ---------------- fused QKV GEMM + f32->bf16 convert, BM=64 x BN=128 ------
// z=0: Qb = q@wqT^T (scaled); z=1: Kb = k@wkT^T; z=2 swapped: VT = wvT@v^T.
// 64-row operand lives in As (4 chunks; wave w stages chunk w); 128-row
// operand in Bs (8 chunks; wave w stages 2w,2w+1). The f32 operand (A for
// z<2, B for z=2) is reg-staged (2x float4 -> cvt -> ds_write_b128 at
// base+lane*16); the bf16 weight operand uses global_load_lds.
// grid (64, 8, 3): z<2 -> row0=bx*64, n0=by*128; z=2 -> flat=by*64+bx,
// row0=(flat>>5)*64 (wvT rows, 16 blocks), n0=(flat&31)*128 (seq, 32 blocks).
__global__ __launch_bounds__(256) void gemm_qkv(const float* __restrict__ Xq,
                                                const float* __restrict__ Xk,
                                                const float* __restrict__ Xv,
                                                const u16* __restrict__ WT,
                                                u16* __restrict__ Qb,
                                                u16* __restrict__ Kb,
                                                u16* __restrict__ VTb) {
  __shared__ u16 As[64 * 32];    // 4 KB: 64-row tile
  __shared__ u16 Bs[128 * 32];   // 8 KB: 128-row tile
  const int z = blockIdx.z;
  const u16* Gbf;      // bf16 operand (gload_lds)
  const float* Gf32;   // f32 operand (reg-staged)
  int row0, n0;
  if (z == 2) {
    Gbf = WT + 2097152;             // A = wvT [1024][1024] (64-row tile)
    Gf32 = Xv;                      // B = value rows (128-row tile)
    const int flat = blockIdx.y * 64 + blockIdx.x;   // 0..511
    row0 = (flat >> 5) * 64;        // 16 row-blocks over 1024
    n0 = (flat & 31) * 128;         // 32 col-blocks over 4096
  } else {
    Gf32 = z ? Xk : Xq;             // A = x rows (64-row tile)
    Gbf = WT + (size_t)z * 1048576; // B = wT (128-row tile)
    row0 = blockIdx.x * 64;         // 64 row-blocks over 4096
    n0 = blockIdx.y * 128;          // 8 col-blocks over 1024
  }
  const int tid = threadIdx.x;
  const int w = tid >> 6, lane = tid & 63;
  const int g = lane >> 4, c = lane & 15;
  const int wr = w >> 1, wc = w & 1;   // wr: 32-row group, wc: 64-col group

  f32x4 acc[2][4];
#pragma unroll
  for (int i = 0; i < 2; ++i)
#pragma unroll
    for (int j = 0; j < 4; ++j) acc[i][j] = (f32x4){0.f, 0.f, 0.f, 0.f};

  const int sub = lane >> 2;                       // row within 16-row chunk
  const int kq = lane & 3;                         // k-group slot
  const int ksrc = (kq ^ ((sub >> 1) & 3)) * 8;    // swizzled source k-group
  const int fsw = ((c >> 1) & 3);                  // frag-read swizzle key

  for (int kt = 0; kt < 32; ++kt) {
    const int k0 = kt * 32;
    if (z == 2) {
      // As <- wvT chunk w (gload); Bs <- value chunks 2w,2w+1 (reg+cvt)
      gload_lds16(Gbf + (size_t)(row0 + w * 16 + sub) * 1024 + k0 + ksrc,
                  (char*)As + w * 1024);
#pragma unroll
      for (int it = 0; it < 2; ++it) {
        const int ch = w * 2 + it;
        const float4* p = (const float4*)(Gf32 + (size_t)(n0 + ch * 16 + sub) * 1024 + k0 + ksrc);
        const float4 aa = p[0], bb = p[1];
        s16x8 o;
        o[0] = (short)to_bf16(aa.x); o[1] = (short)to_bf16(aa.y);
        o[2] = (short)to_bf16(aa.z); o[3] = (short)to_bf16(aa.w);
        o[4] = (short)to_bf16(bb.x); o[5] = (short)to_bf16(bb.y);
        o[6] = (short)to_bf16(bb.z); o[7] = (short)to_bf16(bb.w);
        *(s16x8*)((char*)Bs + ch * 1024 + lane * 16) = o;
      }
    } else {
      // As <- x chunk w (reg+cvt); Bs <- wT chunks 2w,2w+1 (gload)
      {
        const float4* p = (const float4*)(Gf32 + (size_t)(row0 + w * 16 + sub) * 1024 + k0 + ksrc);
        const float4 aa = p[0], bb = p[1];
        s16x8 o;
        o[0] = (short)to_bf16(aa.x); o[1] = (short)to_bf16(aa.y);
        o[2] = (short)to_bf16(aa.z); o[3] = (short)to_bf16(aa.w);
        o[4] = (short)to_bf16(bb.x); o[5] = (short)to_bf16(bb.y);
        o[6] = (short)to_bf16(bb.z); o[7] = (short)to_bf16(bb.w);
        *(s16x8*)((char*)As + w * 1024 + lane * 16) = o;
      }
#pragma unroll
      for (int it = 0; it < 2; ++it) {
        const int ch = w * 2 + it;
        gload_lds16(Gbf + (size_t)(n0 + ch * 16 + sub) * 1024 + k0 + ksrc,
                    (char*)Bs + ch * 1024);
      }
    }
    __syncthreads();

    bf16x8 af[2], bfr[4];
#pragma unroll
    for (int mi = 0; mi < 2; ++mi)
      af[mi] = frag_cast(*(const s16x8*)((const char*)As + (wr * 32 + mi * 16 + c) * 64 + ((g ^ fsw) << 4)));
#pragma unroll
    for (int ni = 0; ni < 4; ++ni)
      bfr[ni] = frag_cast(*(const s16x8*)((const char*)Bs + (wc * 64 + ni * 16 + c) * 64 + ((g ^ fsw) << 4)));
#pragma unroll
    for (int mi = 0; mi < 2; ++mi)
#pragma unroll
      for (int ni = 0; ni < 4; ++ni)
        acc[mi][ni] = mfma16(af[mi], bfr[ni], acc[mi][ni]);
    __syncthreads();
  }

  const float sc = (z == 0) ? QSC : 1.0f;
#pragma unroll
  for (int mi = 0; mi < 2; ++mi) {
    const int rowb = row0 + wr * 32 + mi * 16 + g * 4;
#pragma unroll
    for (int ni = 0; ni < 4; ++ni) {
      const int col = n0 + wc * 64 + ni * 16 + c;
#pragma unroll
      for (int r = 0; r < 4; ++r) {
        const int row = rowb + r;
        const float v = acc[mi][ni][r] * sc;
        if (z == 2) {
          // row = h*64+d, col = b*2048+s
          const int hh = row >> 6, d = row & 63;
          const int bb = col >> 11, s = col & 2047;
          VTb[((size_t)((bb * 16 + hh) * 64 + d)) * 2048 + s] = to_bf16(v);
        } else {
          u16* C = z == 0 ? Qb : Kb;
          C[(size_t)row * 1024 + col] = to_bf16(v);
        }
      }
    }
  }
}

// ---------------- out projection GEMM: BM=64, BN=128, f32 out ------------
__global__ __launch_bounds__(256) void gemm_out(const u16* __restrict__ A,
                                                const u16* __restrict__ BT,
                                                float* __restrict__ C) {
  __shared__ u16 As[64 * 32];
  __shared__ u16 Bs[128 * 32];
  const int tid = threadIdx.x;
  const int w = tid >> 6, lane = tid & 63;
  const int g = lane >> 4, c = lane & 15;
  const int wr = w >> 1, wc = w & 1;
  const int row0 = blockIdx.x * 64;
  const int n0 = blockIdx.y * 128;

  f32x4 acc[2][4];
#pragma unroll
  for (int i = 0; i < 2; ++i)
#pragma unroll
    for (int j = 0; j < 4; ++j) acc[i][j] = (f32x4){0.f, 0.f, 0.f, 0.f};

  const int sub = lane >> 2;
  const int kq = lane & 3;
  const int ksrc = (kq ^ ((sub >> 1) & 3)) * 8;
  const int fsw = ((c >> 1) & 3);

  for (int kt = 0; kt < 32; ++kt) {
    const int k0 = kt * 32;
    {
      const int row = w * 16 + sub;
      gload_lds16(A + (size_t)(row0 + row) * 1024 + k0 + ksrc, (char*)As + w * 1024);
    }
#pragma unroll
    for (int it = 0; it < 2; ++it) {
      const int ch = w * 2 + it;
      const int row = ch * 16 + sub;
      gload_lds16(BT + (size_t)(n0 + row) * 1024 + k0 + ksrc, (char*)Bs + ch * 1024);
    }
    __syncthreads();

    bf16x8 af[2], bfr[4];
#pragma unroll
    for (int mi = 0; mi < 2; ++mi)
      af[mi] = frag_cast(*(const s16x8*)((const char*)As + (wr * 32 + mi * 16 + c) * 64 + ((g ^ fsw) << 4)));
#pragma unroll
    for (int ni = 0; ni < 4; ++ni)
      bfr[ni] = frag_cast(*(const s16x8*)((const char*)Bs + (wc * 64 + ni * 16 + c) * 64 + ((g ^ fsw) << 4)));
#pragma unroll
    for (int mi = 0; mi < 2; ++mi)
#pragma unroll
      for (int ni = 0; ni < 4; ++ni)
        acc[mi][ni] = mfma16(af[mi], bfr[ni], acc[mi][ni]);
    __syncthreads();
  }

#pragma unroll
  for (int mi = 0; mi < 2; ++mi) {
    const int rowb = row0 + wr * 32 + mi * 16 + g * 4;
#pragma unroll
    for (int ni = 0; ni < 4; ++ni) {
      const int col = n0 + wc * 64 + ni * 16 + c;
#pragma unroll
      for (int r = 0; r < 4; ++r)
        C[(size_t)(rowb + r) * 1024 + col] = acc[mi][ni][r];
    }
  }
}

// ---------------- causal flash attention, 8-wave, KVBLK=128 ---------------
// (R8 version verbatim — measured 39.3us.) grid (40, 32) remapped XCD-wise.
// Slice covers <=4 kv tile-pairs (ns=(x+4)>>2; 40 slices/bh). 8 waves x 16
// q-rows. Permuted-K LDS slot (kv&0x63)|((kv&4)<<2)|((kv&0x18)>>1); QK^T
// C-slot (kvf,g,r) holds kv=32(kvf>>1)+4(kvf&1)+8g+r -> PV A-frags packed in
// place. l via ones-MFMA. Writes bf16 partial O + f32 (m,l).
__global__ __launch_bounds__(512, 4) void attn_fwd(const u16* __restrict__ Qb,
                                                   const u16* __restrict__ Kb,
                                                   const u16* __restrict__ VTb,
                                                   u16* __restrict__ PO,
                                                   float* __restrict__ ML) {
  __shared__ u16 Ks[2][128 * 64];   // [buf][slot][d] swizzled   (32 KB)
  __shared__ u16 VTs[2][64 * 128];  // [buf][d][kv] swizzled     (32 KB)

  const int tid = threadIdx.x;
  const int w = tid >> 6, lane = tid & 63;
  const int g = lane >> 4, c = lane & 15;

  // XCD-aware remap: flat -> logical so each XCD gets 4 consecutive bh
  const int flat = blockIdx.x + 40 * blockIdx.y;
  const int logical = (flat & 7) * 160 + (flat >> 3);
  const int slice_id = logical % 40;
  const int bh = logical / 40;
  const int b = bh >> 4, h = bh & 15;

  // decode slice id -> (q-block x, slice sid); ns(x) = (x+4)>>2 over pairs
  int sid = slice_id, x = 0;
  for (; x < 16; ++x) {
    const int ns_ = (x + 4) >> 2;
    if (sid < ns_) break;
    sid -= ns_;
  }
  const int ns = (x + 4) >> 2;
  const int np = x + 1;                       // kv tile-pairs for q-block x
  const int t0 = (sid * np) / ns, t1 = ((sid + 1) * np) / ns;
  const int sg = slice_id + 40 * bh;          // global slice id
  const int q0w = x * 128 + w * 16;           // this wave's first q row

  // Q fragments (B-operand: n=q, k=d) in registers
  bf16x8 qfr[2];
#pragma unroll
  for (int ch = 0; ch < 2; ++ch)
    qfr[ch] = frag_cast(*(const s16x8*)(Qb + (size_t)(b * SEQ + q0w + c) * 1024 + h * 64 + ch * 32 + g * 8));

  s16x8 ones_s;
#pragma unroll
  for (int j = 0; j < 8; ++j) ones_s[j] = (short)0x3F80;  // bf16 1.0
  const bf16x8 onesf = frag_cast(ones_s);

  f32x4 oacc[4];
#pragma unroll
  for (int j = 0; j < 4; ++j) oacc[j] = (f32x4){0.f, 0.f, 0.f, 0.f};
  f32x4 lacc = (f32x4){0.f, 0.f, 0.f, 0.f};
  float m_run = -1e30f;

  // staging geometry
  const int srow = tid >> 3;        // K: 0..63 (+64 on 2nd pass)
  const int scol = (tid & 7) * 8;   // K col elems
  const int vd = tid >> 4;          // V: 0..31 (+32 on 2nd pass)
  const int vcol = (tid & 15) * 8;  // V col elems (kv within pair)

  s16x8 kreg[2], vreg[2];
#define LOADKV(T)                                                                              \
  {                                                                                            \
    const int kv0_ = (T)*128;                                                                  \
    _Pragma("unroll") for (int it = 0; it < 2; ++it) {                                         \
      kreg[it] = *(const s16x8*)(Kb + (size_t)(b * SEQ + kv0_ + srow + it * 64) * 1024 +       \
                                 h * 64 + scol);                                               \
      vreg[it] = *(const s16x8*)(VTb + ((size_t)(bh * 64 + vd + it * 32)) * 2048 + kv0_ +      \
                                 vcol);                                                        \
    }                                                                                          \
  }
#define WRITEKV(BUF)                                                                           \
  {                                                                                            \
    _Pragma("unroll") for (int it = 0; it < 2; ++it) {                                         \
      const int rr_ = srow + it * 64;                                                          \
      const int pr_ = (rr_ & 0x63) | ((rr_ & 4) << 2) | ((rr_ & 0x18) >> 1);                   \
      *(s16x8*)((char*)Ks[BUF] + pr_ * 128 + ((scol * 2) ^ ((pr_ & 7) << 4))) = kreg[it];      \
      const int vr_ = vd + it * 32;                                                            \
      *(s16x8*)((char*)VTs[BUF] + vr_ * 256 + ((vcol * 2) ^ ((vr_ & 7) << 4))) = vreg[it];     \
    }                                                                                          \
  }

  LOADKV(t0);
  WRITEKV(0);
  __syncthreads();

  int cur = 0;
  for (int t = t0; t < t1; ++t) {
    const bool pre = (t + 1 < t1);
    if (pre) LOADKV(t + 1);          // issue early; lands during compute

    const int kv0 = t * 128;
    if (!(kv0 > q0w + 15)) {         // wave has live rows in this pair
      // ---- S^T = K * Q^T over 128 kv: 8 kvf frags
      f32x4 sa[8];
#pragma unroll
      for (int i = 0; i < 8; ++i) sa[i] = (f32x4){0.f, 0.f, 0.f, 0.f};
#pragma unroll
      for (int kvf = 0; kvf < 8; ++kvf) {
        const int kr = kvf * 16 + c;
        const int rb = kr * 128, swz = (kr & 7) << 4;
#pragma unroll
        for (int ch = 0; ch < 2; ++ch) {
          const bf16x8 ak = frag_cast(*(const s16x8*)((char*)Ks[cur] + rb + ((ch * 64 + g * 16) ^ swz)));
          sa[kvf] = mfma16(ak, qfr[ch], sa[kvf]);
        }
      }

      // ---- mask (diagonal pairs only) + tile max
      float mt = -1e30f;
      if (kv0 + 127 > q0w) {         // diagonal pair: mask with permuted kv
        const int q_abs = q0w + c;
#pragma unroll
        for (int kvf = 0; kvf < 8; ++kvf) {
          const int kvb = kv0 + (kvf >> 1) * 32 + (kvf & 1) * 4 + 8 * g;
#pragma unroll
          for (int r = 0; r < 4; ++r) {
            float s = sa[kvf][r];
            if (kvb + r > q_abs) s = -30000.f;
            sa[kvf][r] = s;
            mt = fmaxf(mt, s);
          }
        }
      } else {
#pragma unroll
        for (int kvf = 0; kvf < 8; ++kvf)
#pragma unroll
          for (int r = 0; r < 4; ++r) mt = fmaxf(mt, sa[kvf][r]);
      }
      mt = fmaxf(mt, __shfl_xor(mt, 16));
      mt = fmaxf(mt, __shfl_xor(mt, 32));

      if (__any(mt > m_run + 8.f)) {   // defer-max (T13)
        const float m_new = fmaxf(m_run, mt);
        const float alpha = __builtin_amdgcn_exp2f(m_run - m_new);
        m_run = m_new;
#pragma unroll
        for (int r = 0; r < 4; ++r) {
          const float ar = __shfl(alpha, g * 4 + r);
#pragma unroll
          for (int df = 0; df < 4; ++df) oacc[df][r] *= ar;
          lacc[r] *= ar;
        }
      }

      // ---- exp2 + pack in place into PV A-fragments (4 ch of 32 kv)
      s16x8 pk[4];
#pragma unroll
      for (int kvf = 0; kvf < 8; ++kvf)
#pragma unroll
        for (int r = 0; r < 4; ++r) {
          const float p = __builtin_amdgcn_exp2f(sa[kvf][r] - m_run);
          pk[kvf >> 1][(kvf & 1) * 4 + r] = (short)to_bf16(p);
        }

      // ---- O += P*V ; l += P*1 (row-sum via MFMA, no shfl)
#pragma unroll
      for (int ch = 0; ch < 4; ++ch) {
        const bf16x8 ap = frag_cast(pk[ch]);
#pragma unroll
        for (int df = 0; df < 4; ++df) {
          const int dr = df * 16 + c;
          const bf16x8 bv = frag_cast(*(const s16x8*)((char*)VTs[cur] + dr * 256 +
                                                      ((ch * 64 + g * 16) ^ ((dr & 7) << 4))));
          oacc[df] = mfma16(ap, bv, oacc[df]);
        }
        lacc = mfma16(ap, onesf, lacc);
      }
    }

    if (pre) WRITEKV(cur ^ 1);   // write next buffer (others still read cur)
    __syncthreads();
    cur ^= 1;
  }

  // epilogue: bf16 unnormalized partial O; f32 (m,l)
  const size_t pob = (size_t)sg * 8192;
#pragma unroll
  for (int r = 0; r < 4; ++r) {
    const int row = w * 16 + g * 4 + r;
#pragma unroll
    for (int df = 0; df < 4; ++df)
      PO[pob + row * 64 + df * 16 + c] = to_bf16(oacc[df][r]);
  }
  if (g == 0)
    ML[sg * 256 + (w * 16 + c) * 2 + 0] = m_run;     // m for q=c
  if (c == 0) {
#pragma unroll
    for (int r = 0; r < 4; ++r)
      ML[sg * 256 + (w * 16 + g * 4 + r) * 2 + 1] = lacc[r];  // l for q=4g+r
  }
}

// ---------------- merge split-kv partials -> bf16 Ob ----------------------
// grid (16, 32), 512 thr: x = q-block (128 rows), y = bh. row=tid/4, 16 cols.
__global__ __launch_bounds__(512) void attn_merge(const u16* __restrict__ PO,
                                                  const float* __restrict__ ML,
                                                  u16* __restrict__ Ob) {
  const int x = blockIdx.x, bh = blockIdx.y;
  const int b = bh >> 4, h = bh & 15;
  const int tid = threadIdx.x;
  const int row = tid >> 2, c0 = (tid & 3) << 4;

  int base = 0;
  for (int xp = 0; xp < x; ++xp) base += (xp + 4) >> 2;
  const int ns = (x + 4) >> 2;
  const int sg0 = base + 40 * bh;

  float m[4], l[4], a[4];
  float M = -3e38f;
  for (int i = 0; i < ns; ++i) {
    m[i] = ML[(sg0 + i) * 256 + row * 2 + 0];
    l[i] = ML[(sg0 + i) * 256 + row * 2 + 1];
    M = fmaxf(M, m[i]);
  }
  float denom = 0.f;
  for (int i = 0; i < ns; ++i) {
    a[i] = __builtin_amdgcn_exp2f(m[i] - M);
    denom += a[i] * l[i];
  }
  const float inv = 1.f / denom;

  float o[16];
#pragma unroll
  for (int j = 0; j < 16; ++j) o[j] = 0.f;
  for (int i = 0; i < ns; ++i) {
    const float s = a[i] * inv;
    const u16* p = PO + (size_t)(sg0 + i) * 8192 + row * 64 + c0;
    const s16x8 v0 = *(const s16x8*)p;
    const s16x8 v1 = *(const s16x8*)(p + 8);
#pragma unroll
    for (int j = 0; j < 8; ++j) {
      o[j] += s * from_bf16((u16)v0[j]);
      o[8 + j] += s * from_bf16((u16)v1[j]);
    }
  }

  s16x8 lo, hi;
#pragma unroll
  for (int j = 0; j < 8; ++j) {
    lo[j] = (short)to_bf16(o[j]);
    hi[j] = (short)to_bf16(o[8 + j]);
  }
  u16* dst = Ob + (size_t)(b * SEQ + x * 128 + row) * 1024 + h * 64 + c0;
  *(s16x8*)dst = lo;
  *(s16x8*)(dst + 8) = hi;
}

// --------------------------------------------------------------------------
extern "C" void kernel_launch(void* const* d_in, const int* in_sizes, int n_in,
                              void* d_out, int out_size, void* d_ws, size_t ws_size,
                              hipStream_t stream) {
  const float* query = (const float*)d_in[0];
  const float* key_ = (const float*)d_in[1];
  const float* value = (const float*)d_in[2];
  const float* w_q = (const float*)d_in[3];
  const float* w_k = (const float*)d_in[4];
  const float* w_v = (const float*)d_in[5];
  const float* w_o = (const float*)d_in[6];

  char* ws = (char*)d_ws;
  u16* PO = (u16*)(ws + 0);
  u16* wT = (u16*)(ws + 25165824);
  float* ML = (float*)(ws + 25165824);   // aliases wqT/wkT (dead post-qkv)
  u16* Qb = (u16*)(ws + 33554432);
  u16* Kb = (u16*)(ws + 41943040);
  u16* VTb = (u16*)(ws + 50331648);
  u16* Ob = (u16*)(ws + 58720256);

  transpose_w<<<dim3(32, 32, 4), dim3(32, 8), 0, stream>>>(w_q, w_k, w_v, w_o, wT);
  gemm_qkv<<<dim3(64, 8, 3), 256, 0, stream>>>(query, key_, value, wT, Qb, Kb, VTb);
  attn_fwd<<<dim3(40, 32), 512, 0, stream>>>(Qb, Kb, VTb, PO, ML);
  attn_merge<<<dim3(16, 32), 512, 0, stream>>>(PO, ML, Ob);
  gemm_out<<<dim3(64, 8), 256, 0, stream>>>(Ob, wT + 3145728, (float*)d_out);
}

// Round 16
// 121.579 us; speedup vs baseline: 1.8044x; 1.0870x over previous
//
#include <hip/hip_runtime.h>

// MultiHeadAttention: x@Wq/Wk/Wv -> causal flash attn -> @Wo
// B=2 S=2048 H=16 D=64 HIDDEN=1024. All MFMA bf16 16x16x32, f32 accum.
//
// R15 = R11 (best: 111.4us) with ONE change: gemm_qkv K-loop processes BK=64
// (two 32-wide halves) per barrier pair: 32 MFMA between barriers instead of
// 16, halving barrier count + f32-latency exposures (R7's verified
// amortization move; tile stays 128^2 per R14's intensity lesson).
// R14's BM=64 qkv REVERTED (12.3% MfmaUtil: worse per-step amortization).
//
// Workspace map (64 MiB), with region reuse:
//   [0)         PO bf16 partial O: 1280 slices x 128 rows x 64 d (21 MiB)
//   [25165824)  ML f32: 1280 slices x 128 rows x {m,l}  (1.31 MiB)
//   [31457280)  woT (live until gemm_out)   [wT block: 25165824 + z*2MiB]
//   [33554432)  Qb  bf16 [4096][1024]  (pre-scaled by 0.125*log2(e))
//   [41943040)  Kb  bf16 [4096][1024]
//   [50331648)  VTb bf16 [b][h][d][s] = [2][16][64][2048]
//   [58720256)  Ob  bf16 [4096][1024]
//   NOTE: ML aliases wqT/wkT which are DEAD after gemm_qkv completes.

using u16 = unsigned short;
typedef __bf16 bf16x8 __attribute__((ext_vector_type(8)));
typedef short  s16x8  __attribute__((ext_vector_type(8)));
typedef float  f32x4  __attribute__((ext_vector_type(4)));

#define SEQ   2048
#define QSC   0.18033688f   /* 0.125 * log2(e) */

__device__ __forceinline__ u16 to_bf16(float f) {
  return __builtin_bit_cast(u16, (__bf16)f);
}
__device__ __forceinline__ float from_bf16(u16 v) {
  return __builtin_bit_cast(float, ((unsigned)v) << 16);
}
__device__ __forceinline__ bf16x8 frag_cast(s16x8 v) {
  return __builtin_bit_cast(bf16x8, v);
}
__device__ __forceinline__ f32x4 mfma16(bf16x8 a, bf16x8 b, f32x4 c) {
  return __builtin_amdgcn_mfma_f32_16x16x32_bf16(a, b, c, 0, 0, 0);
}
__device__ __forceinline__ void gload_lds16(const void* g, void* l) {
  __builtin_amdgcn_global_load_lds(
      (const __attribute__((address_space(1))) void*)g,
      (__attribute__((address_space(3))) void*)l, 16, 0, 0);
}

// ---------------- weight transpose+convert: w[K][N] f32 -> wT[N][K] bf16 --
__global__ __launch_bounds__(256) void transpose_w(const float* __restrict__ wq,
                                                   const float* __restrict__ wk,
                                                   const float* __restrict__ wv,
                                                   const float* __restrict__ wo,
                                                   u16* __restrict__ wT) {
  __shared__ float tile[32][33];
  const float* src = blockIdx.z == 0 ? wq : blockIdx.z == 1 ? wk
                     : blockIdx.z == 2 ? wv : wo;
  u16* dst = wT + (size_t)blockIdx.z * 1048576;
  const int x0 = blockIdx.x * 32, y0 = blockIdx.y * 32;
  const int tx = threadIdx.x, ty = threadIdx.y;  // block (32,8)
#pragma unroll
  for (int i = 0; i < 4; ++i)
    tile[ty + i * 8][tx] = src[(size_t)(y0 + ty + i * 8) * 1024 + x0 + tx];
  __syncthreads();
#pragma unroll
  for (int i = 0; i < 4; ++i)
    dst[(size_t)(x0 + ty + i * 8) * 1024 + y0 + tx] = to_bf16(tile[tx][ty + i * 8]);
}

// ---------------- fused QKV GEMM + f32->bf16 convert, BK=64 ---------------
// z=0: Qb = q@wqT^T (scaled); z=1: Kb = k@wkT^T; z=2 swapped: VT = wvT@v^T.
// LDS layout: [ch 0..7][hf 0..1][16 rows][32 elems] (each staged 1KB block
// contiguous so global_load_lds lands linearly). Frag read adds ks*1024.
__global__ __launch_bounds__(256) void gemm_qkv(const float* __restrict__ Xq,
                                                const float* __restrict__ Xk,
                                                const float* __restrict__ Xv,
                                                const u16* __restrict__ WT,
                                                u16* __restrict__ Qb,
                                                u16* __restrict__ Kb,
                                                u16* __restrict__ VTb) {
  __shared__ u16 As[128 * 64];   // 16 KB
  __shared__ u16 Bs[128 * 64];   // 16 KB
  const int z = blockIdx.z;
  const u16* Gbf;      // bf16 operand (gload_lds)
  const float* Gf32;   // f32 operand (reg-staged)
  int row0, n0;
  if (z == 2) {
    Gbf = WT + 2097152;             // A = wvT [1024][1024]
    Gf32 = Xv;                      // B = value rows (seq)
    row0 = blockIdx.y * 128;        // 8 row-blocks
    n0 = blockIdx.x * 128;          // 32 col-blocks
  } else {
    Gf32 = z ? Xk : Xq;             // A = x rows (seq)
    Gbf = WT + (size_t)z * 1048576; // B = wT
    row0 = blockIdx.x * 128;
    n0 = blockIdx.y * 128;
  }
  const int frow0 = (z == 2) ? n0 : row0;   // f32 operand tile base row
  const int wrow0 = (z == 2) ? row0 : n0;   // weight operand tile base row

  const int tid = threadIdx.x;
  const int w = tid >> 6, lane = tid & 63;
  const int g = lane >> 4, c = lane & 15;
  const int wr = w >> 1, wc = w & 1;

  f32x4 acc[4][4];
#pragma unroll
  for (int i = 0; i < 4; ++i)
#pragma unroll
    for (int j = 0; j < 4; ++j) acc[i][j] = (f32x4){0.f, 0.f, 0.f, 0.f};

  const int sub = lane >> 2;                       // row within 16-row chunk
  const int kq = lane & 3;                         // k-group slot
  const int ksrc = (kq ^ ((sub >> 1) & 3)) * 8;    // swizzled source k-group
  const int fsw = ((c >> 1) & 3);                  // frag-read swizzle key

  char* fdst = (z == 2) ? (char*)Bs : (char*)As;   // f32 operand dest
  char* wdst = (z == 2) ? (char*)As : (char*)Bs;   // weight operand dest

  for (int kt = 0; kt < 16; ++kt) {
    const int k0 = kt * 64;
    float4 fa[2][2][2];   // [it][hf][lo/hi]
#pragma unroll
    for (int it = 0; it < 2; ++it) {
      const int ch = w * 2 + it;
#pragma unroll
      for (int hf = 0; hf < 2; ++hf) {
        gload_lds16(Gbf + (size_t)(wrow0 + ch * 16 + sub) * 1024 + k0 + hf * 32 + ksrc,
                    wdst + ch * 2048 + hf * 1024);
        const float4* p =
            (const float4*)(Gf32 + (size_t)(frow0 + ch * 16 + sub) * 1024 + k0 + hf * 32 + ksrc);
        fa[it][hf][0] = p[0];
        fa[it][hf][1] = p[1];
      }
    }
#pragma unroll
    for (int it = 0; it < 2; ++it)
#pragma unroll
      for (int hf = 0; hf < 2; ++hf) {
        s16x8 o;
        o[0] = (short)to_bf16(fa[it][hf][0].x); o[1] = (short)to_bf16(fa[it][hf][0].y);
        o[2] = (short)to_bf16(fa[it][hf][0].z); o[3] = (short)to_bf16(fa[it][hf][0].w);
        o[4] = (short)to_bf16(fa[it][hf][1].x); o[5] = (short)to_bf16(fa[it][hf][1].y);
        o[6] = (short)to_bf16(fa[it][hf][1].z); o[7] = (short)to_bf16(fa[it][hf][1].w);
        *(s16x8*)(fdst + (w * 2 + it) * 2048 + hf * 1024 + lane * 16) = o;
      }
    __syncthreads();

#pragma unroll
    for (int ks = 0; ks < 2; ++ks) {
      bf16x8 af[4], bfr[4];
#pragma unroll
      for (int mi = 0; mi < 4; ++mi)
        af[mi] = frag_cast(*(const s16x8*)((const char*)As + (wr * 4 + mi) * 2048 + ks * 1024 +
                                           c * 64 + ((g ^ fsw) << 4)));
#pragma unroll
      for (int ni = 0; ni < 4; ++ni)
        bfr[ni] = frag_cast(*(const s16x8*)((const char*)Bs + (wc * 4 + ni) * 2048 + ks * 1024 +
                                            c * 64 + ((g ^ fsw) << 4)));
#pragma unroll
      for (int mi = 0; mi < 4; ++mi)
#pragma unroll
        for (int ni = 0; ni < 4; ++ni)
          acc[mi][ni] = mfma16(af[mi], bfr[ni], acc[mi][ni]);
    }
    __syncthreads();
  }

  const float sc = (z == 0) ? QSC : 1.0f;
#pragma unroll
  for (int mi = 0; mi < 4; ++mi) {
    const int rowb = row0 + wr * 64 + mi * 16 + g * 4;
#pragma unroll
    for (int ni = 0; ni < 4; ++ni) {
      const int col = n0 + wc * 64 + ni * 16 + c;
#pragma unroll
      for (int r = 0; r < 4; ++r) {
        const int row = rowb + r;
        const float v = acc[mi][ni][r] * sc;
        if (z == 2) {
          // row = h*64+d, col = b*2048+s
          const int hh = row >> 6, d = row & 63;
          const int bb = col >> 11, s = col & 2047;
          VTb[((size_t)((bb * 16 + hh) * 64 + d)) * 2048 + s] = to_bf16(v);
        } else {
          u16* C = z == 0 ? Qb : Kb;
          C[(size_t)row * 1024 + col] = to_bf16(v);
        }
      }
    }
  }
}

// ---------------- out projection GEMM: BM=64, BN=128, f32 out ------------
__global__ __launch_bounds__(256) void gemm_out(const u16* __restrict__ A,
                                                const u16* __restrict__ BT,
                                                float* __restrict__ C) {
  __shared__ u16 As[64 * 32];
  __shared__ u16 Bs[128 * 32];
  const int tid = threadIdx.x;
  const int w = tid >> 6, lane = tid & 63;
  const int g = lane >> 4, c = lane & 15;
  const int wr = w >> 1, wc = w & 1;
  const int row0 = blockIdx.x * 64;
  const int n0 = blockIdx.y * 128;

  f32x4 acc[2][4];
#pragma unroll
  for (int i = 0; i < 2; ++i)
#pragma unroll
    for (int j = 0; j < 4; ++j) acc[i][j] = (f32x4){0.f, 0.f, 0.f, 0.f};

  const int sub = lane >> 2;
  const int kq = lane & 3;
  const int ksrc = (kq ^ ((sub >> 1) & 3)) * 8;
  const int fsw = ((c >> 1) & 3);

  for (int kt = 0; kt < 32; ++kt) {
    const int k0 = kt * 32;
    {
      const int row = w * 16 + sub;
      gload_lds16(A + (size_t)(row0 + row) * 1024 + k0 + ksrc, (char*)As + w * 1024);
    }
#pragma unroll
    for (int it = 0; it < 2; ++it) {
      const int ch = w * 2 + it;
      const int row = ch * 16 + sub;
      gload_lds16(BT + (size_t)(n0 + row) * 1024 + k0 + ksrc, (char*)Bs + ch * 1024);
    }
    __syncthreads();

    bf16x8 af[2], bfr[4];
#pragma unroll
    for (int mi = 0; mi < 2; ++mi)
      af[mi] = frag_cast(*(const s16x8*)((const char*)As + (wr * 32 + mi * 16 + c) * 64 + ((g ^ fsw) << 4)));
#pragma unroll
    for (int ni = 0; ni < 4; ++ni)
      bfr[ni] = frag_cast(*(const s16x8*)((const char*)Bs + (wc * 64 + ni * 16 + c) * 64 + ((g ^ fsw) << 4)));
#pragma unroll
    for (int mi = 0; mi < 2; ++mi)
#pragma unroll
      for (int ni = 0; ni < 4; ++ni)
        acc[mi][ni] = mfma16(af[mi], bfr[ni], acc[mi][ni]);
    __syncthreads();
  }

#pragma unroll
  for (int mi = 0; mi < 2; ++mi) {
    const int rowb = row0 + wr * 32 + mi * 16 + g * 4;
#pragma unroll
    for (int ni = 0; ni < 4; ++ni) {
      const int col = n0 + wc * 64 + ni * 16 + c;
#pragma unroll
      for (int r = 0; r < 4; ++r)
        C[(size_t)(rowb + r) * 1024 + col] = acc[mi][ni][r];
    }
  }
}

// ---------------- causal flash attention, 8-wave, KVBLK=128 ---------------
// (R8 version verbatim — measured 39.3us.) grid (40, 32) remapped XCD-wise.
// Slice covers <=4 kv tile-pairs (ns=(x+4)>>2; 40 slices/bh). 8 waves x 16
// q-rows. Permuted-K LDS slot (kv&0x63)|((kv&4)<<2)|((kv&0x18)>>1); QK^T
// C-slot (kvf,g,r) holds kv=32(kvf>>1)+4(kvf&1)+8g+r -> PV A-frags packed in
// place. l via ones-MFMA. Writes bf16 partial O + f32 (m,l).
__global__ __launch_bounds__(512, 4) void attn_fwd(const u16* __restrict__ Qb,
                                                   const u16* __restrict__ Kb,
                                                   const u16* __restrict__ VTb,
                                                   u16* __restrict__ PO,
                                                   float* __restrict__ ML) {
  __shared__ u16 Ks[2][128 * 64];   // [buf][slot][d] swizzled   (32 KB)
  __shared__ u16 VTs[2][64 * 128];  // [buf][d][kv] swizzled     (32 KB)

  const int tid = threadIdx.x;
  const int w = tid >> 6, lane = tid & 63;
  const int g = lane >> 4, c = lane & 15;

  // XCD-aware remap: flat -> logical so each XCD gets 4 consecutive bh
  const int flat = blockIdx.x + 40 * blockIdx.y;
  const int logical = (flat & 7) * 160 + (flat >> 3);
  const int slice_id = logical % 40;
  const int bh = logical / 40;
  const int b = bh >> 4, h = bh & 15;

  // decode slice id -> (q-block x, slice sid); ns(x) = (x+4)>>2 over pairs
  int sid = slice_id, x = 0;
  for (; x < 16; ++x) {
    const int ns_ = (x + 4) >> 2;
    if (sid < ns_) break;
    sid -= ns_;
  }
  const int ns = (x + 4) >> 2;
  const int np = x + 1;                       // kv tile-pairs for q-block x
  const int t0 = (sid * np) / ns, t1 = ((sid + 1) * np) / ns;
  const int sg = slice_id + 40 * bh;          // global slice id
  const int q0w = x * 128 + w * 16;           // this wave's first q row

  // Q fragments (B-operand: n=q, k=d) in registers
  bf16x8 qfr[2];
#pragma unroll
  for (int ch = 0; ch < 2; ++ch)
    qfr[ch] = frag_cast(*(const s16x8*)(Qb + (size_t)(b * SEQ + q0w + c) * 1024 + h * 64 + ch * 32 + g * 8));

  s16x8 ones_s;
#pragma unroll
  for (int j = 0; j < 8; ++j) ones_s[j] = (short)0x3F80;  // bf16 1.0
  const bf16x8 onesf = frag_cast(ones_s);

  f32x4 oacc[4];
#pragma unroll
  for (int j = 0; j < 4; ++j) oacc[j] = (f32x4){0.f, 0.f, 0.f, 0.f};
  f32x4 lacc = (f32x4){0.f, 0.f, 0.f, 0.f};
  float m_run = -1e30f;

  // staging geometry
  const int srow = tid >> 3;        // K: 0..63 (+64 on 2nd pass)
  const int scol = (tid & 7) * 8;   // K col elems
  const int vd = tid >> 4;          // V: 0..31 (+32 on 2nd pass)
  const int vcol = (tid & 15) * 8;  // V col elems (kv within pair)

  s16x8 kreg[2], vreg[2];
#define LOADKV(T)                                                                              \
  {                                                                                            \
    const int kv0_ = (T)*128;                                                                  \
    _Pragma("unroll") for (int it = 0; it < 2; ++it) {                                         \
      kreg[it] = *(const s16x8*)(Kb + (size_t)(b * SEQ + kv0_ + srow + it * 64) * 1024 +       \
                                 h * 64 + scol);                                               \
      vreg[it] = *(const s16x8*)(VTb + ((size_t)(bh * 64 + vd + it * 32)) * 2048 + kv0_ +      \
                                 vcol);                                                        \
    }                                                                                          \
  }
#define WRITEKV(BUF)                                                                           \
  {                                                                                            \
    _Pragma("unroll") for (int it = 0; it < 2; ++it) {                                         \
      const int rr_ = srow + it * 64;                                                          \
      const int pr_ = (rr_ & 0x63) | ((rr_ & 4) << 2) | ((rr_ & 0x18) >> 1);                   \
      *(s16x8*)((char*)Ks[BUF] + pr_ * 128 + ((scol * 2) ^ ((pr_ & 7) << 4))) = kreg[it];      \
      const int vr_ = vd + it * 32;                                                            \
      *(s16x8*)((char*)VTs[BUF] + vr_ * 256 + ((vcol * 2) ^ ((vr_ & 7) << 4))) = vreg[it];     \
    }                                                                                          \
  }

  LOADKV(t0);
  WRITEKV(0);
  __syncthreads();

  int cur = 0;
  for (int t = t0; t < t1; ++t) {
    const bool pre = (t + 1 < t1);
    if (pre) LOADKV(t + 1);          // issue early; lands during compute

    const int kv0 = t * 128;
    if (!(kv0 > q0w + 15)) {         // wave has live rows in this pair
      // ---- S^T = K * Q^T over 128 kv: 8 kvf frags
      f32x4 sa[8];
#pragma unroll
      for (int i = 0; i < 8; ++i) sa[i] = (f32x4){0.f, 0.f, 0.f, 0.f};
#pragma unroll
      for (int kvf = 0; kvf < 8; ++kvf) {
        const int kr = kvf * 16 + c;
        const int rb = kr * 128, swz = (kr & 7) << 4;
#pragma unroll
        for (int ch = 0; ch < 2; ++ch) {
          const bf16x8 ak = frag_cast(*(const s16x8*)((char*)Ks[cur] + rb + ((ch * 64 + g * 16) ^ swz)));
          sa[kvf] = mfma16(ak, qfr[ch], sa[kvf]);
        }
      }

      // ---- mask (diagonal pairs only) + tile max
      float mt = -1e30f;
      if (kv0 + 127 > q0w) {         // diagonal pair: mask with permuted kv
        const int q_abs = q0w + c;
#pragma unroll
        for (int kvf = 0; kvf < 8; ++kvf) {
          const int kvb = kv0 + (kvf >> 1) * 32 + (kvf & 1) * 4 + 8 * g;
#pragma unroll
          for (int r = 0; r < 4; ++r) {
            float s = sa[kvf][r];
            if (kvb + r > q_abs) s = -30000.f;
            sa[kvf][r] = s;
            mt = fmaxf(mt, s);
          }
        }
      } else {
#pragma unroll
        for (int kvf = 0; kvf < 8; ++kvf)
#pragma unroll
          for (int r = 0; r < 4; ++r) mt = fmaxf(mt, sa[kvf][r]);
      }
      mt = fmaxf(mt, __shfl_xor(mt, 16));
      mt = fmaxf(mt, __shfl_xor(mt, 32));

      if (__any(mt > m_run + 8.f)) {   // defer-max (T13)
        const float m_new = fmaxf(m_run, mt);
        const float alpha = __builtin_amdgcn_exp2f(m_run - m_new);
        m_run = m_new;
#pragma unroll
        for (int r = 0; r < 4; ++r) {
          const float ar = __shfl(alpha, g * 4 + r);
#pragma unroll
          for (int df = 0; df < 4; ++df) oacc[df][r] *= ar;
          lacc[r] *= ar;
        }
      }

      // ---- exp2 + pack in place into PV A-fragments (4 ch of 32 kv)
      s16x8 pk[4];
#pragma unroll
      for (int kvf = 0; kvf < 8; ++kvf)
#pragma unroll
        for (int r = 0; r < 4; ++r) {
          const float p = __builtin_amdgcn_exp2f(sa[kvf][r] - m_run);
          pk[kvf >> 1][(kvf & 1) * 4 + r] = (short)to_bf16(p);
        }

      // ---- O += P*V ; l += P*1 (row-sum via MFMA, no shfl)
#pragma unroll
      for (int ch = 0; ch < 4; ++ch) {
        const bf16x8 ap = frag_cast(pk[ch]);
#pragma unroll
        for (int df = 0; df < 4; ++df) {
          const int dr = df * 16 + c;
          const bf16x8 bv = frag_cast(*(const s16x8*)((char*)VTs[cur] + dr * 256 +
                                                      ((ch * 64 + g * 16) ^ ((dr & 7) << 4))));
          oacc[df] = mfma16(ap, bv, oacc[df]);
        }
        lacc = mfma16(ap, onesf, lacc);
      }
    }

    if (pre) WRITEKV(cur ^ 1);   // write next buffer (others still read cur)
    __syncthreads();
    cur ^= 1;
  }

  // epilogue: bf16 unnormalized partial O; f32 (m,l)
  const size_t pob = (size_t)sg * 8192;
#pragma unroll
  for (int r = 0; r < 4; ++r) {
    const int row = w * 16 + g * 4 + r;
#pragma unroll
    for (int df = 0; df < 4; ++df)
      PO[pob + row * 64 + df * 16 + c] = to_bf16(oacc[df][r]);
  }
  if (g == 0)
    ML[sg * 256 + (w * 16 + c) * 2 + 0] = m_run;     // m for q=c
  if (c == 0) {
#pragma unroll
    for (int r = 0; r < 4; ++r)
      ML[sg * 256 + (w * 16 + g * 4 + r) * 2 + 1] = lacc[r];  // l for q=4g+r
  }
}

// ---------------- merge split-kv partials -> bf16 Ob ----------------------
// grid (16, 32), 512 thr: x = q-block (128 rows), y = bh. row=tid/4, 16 cols.
__global__ __launch_bounds__(512) void attn_merge(const u16* __restrict__ PO,
                                                  const float* __restrict__ ML,
                                                  u16* __restrict__ Ob) {
  const int x = blockIdx.x, bh = blockIdx.y;
  const int b = bh >> 4, h = bh & 15;
  const int tid = threadIdx.x;
  const int row = tid >> 2, c0 = (tid & 3) << 4;

  int base = 0;
  for (int xp = 0; xp < x; ++xp) base += (xp + 4) >> 2;
  const int ns = (x + 4) >> 2;
  const int sg0 = base + 40 * bh;

  float m[4], l[4], a[4];
  float M = -3e38f;
  for (int i = 0; i < ns; ++i) {
    m[i] = ML[(sg0 + i) * 256 + row * 2 + 0];
    l[i] = ML[(sg0 + i) * 256 + row * 2 + 1];
    M = fmaxf(M, m[i]);
  }
  float denom = 0.f;
  for (int i = 0; i < ns; ++i) {
    a[i] = __builtin_amdgcn_exp2f(m[i] - M);
    denom += a[i] * l[i];
  }
  const float inv = 1.f / denom;

  float o[16];
#pragma unroll
  for (int j = 0; j < 16; ++j) o[j] = 0.f;
  for (int i = 0; i < ns; ++i) {
    const float s = a[i] * inv;
    const u16* p = PO + (size_t)(sg0 + i) * 8192 + row * 64 + c0;
    const s16x8 v0 = *(const s16x8*)p;
    const s16x8 v1 = *(const s16x8*)(p + 8);
#pragma unroll
    for (int j = 0; j < 8; ++j) {
      o[j] += s * from_bf16((u16)v0[j]);
      o[8 + j] += s * from_bf16((u16)v1[j]);
    }
  }

  s16x8 lo, hi;
#pragma unroll
  for (int j = 0; j < 8; ++j) {
    lo[j] = (short)to_bf16(o[j]);
    hi[j] = (short)to_bf16(o[8 + j]);
  }
  u16* dst = Ob + (size_t)(b * SEQ + x * 128 + row) * 1024 + h * 64 + c0;
  *(s16x8*)dst = lo;
  *(s16x8*)(dst + 8) = hi;
}

// --------------------------------------------------------------------------
extern "C" void kernel_launch(void* const* d_in, const int* in_sizes, int n_in,
                              void* d_out, int out_size, void* d_ws, size_t ws_size,
                              hipStream_t stream) {
  const float* query = (const float*)d_in[0];
  const float* key_ = (const float*)d_in[1];
  const float* value = (const float*)d_in[2];
  const float* w_q = (const float*)d_in[3];
  const float* w_k = (const float*)d_in[4];
  const float* w_v = (const float*)d_in[5];
  const float* w_o = (const float*)d_in[6];

  char* ws = (char*)d_ws;
  u16* PO = (u16*)(ws + 0);
  u16* wT = (u16*)(ws + 25165824);
  float* ML = (float*)(ws + 25165824);   // aliases wqT/wkT (dead post-qkv)
  u16* Qb = (u16*)(ws + 33554432);
  u16* Kb = (u16*)(ws + 41943040);
  u16* VTb = (u16*)(ws + 50331648);
  u16* Ob = (u16*)(ws + 58720256);

  transpose_w<<<dim3(32, 32, 4), dim3(32, 8), 0, stream>>>(w_q, w_k, w_v, w_o, wT);
  gemm_qkv<<<dim3(32, 8, 3), 256, 0, stream>>>(query, key_, value, wT, Qb, Kb, VTb);
  attn_fwd<<<dim3(40, 32), 512, 0, stream>>>(Qb, Kb, VTb, PO, ML);
  attn_merge<<<dim3(16, 32), 512, 0, stream>>>(PO, ML, Ob);
  gemm_out<<<dim3(64, 8), 256, 0, stream>>>(Ob, wT + 3145728, (float*)d_out);
}

// Round 17
// 119.623 us; speedup vs baseline: 1.8339x; 1.0164x over previous
//
#include <hip/hip_runtime.h>

// MultiHeadAttention: x@Wq/Wk/Wv -> causal flash attn -> @Wo
// B=2 S=2048 H=16 D=64 HIDDEN=1024. All MFMA bf16 16x16x32, f32 accum.
//
// R16 = R11 with gemm_qkv split-K across wave-quads:
//  - 512-thread blocks; quad 0 (waves 0-3) K[0,512), quad 1 K[512,1024),
//    same 128^2 tile, per-quad 16KB As/Bs (32KB). Loop body byte-identical
//    to R11 (VGPR-76 tier preserved) -> 3 blocks/CU x 8 waves = 24 waves/CU
//    (vs 12) and serial K-path 32 -> 16 steps. Exact f32 LDS reduction
//    (element-major, conflict-free, 2x32KB passes); quad 0 writes C.
//  - R15's BK=64 REVERTED (VGPR 100 -> occupancy tier drop, +8us).
//
// Workspace map (64 MiB), with region reuse:
//   [0)         PO bf16 partial O: 1280 slices x 128 rows x 64 d (21 MiB)
//   [25165824)  ML f32: 1280 slices x 128 rows x {m,l}  (1.31 MiB)
//   [31457280)  woT (live until gemm_out)   [wT block: 25165824 + z*2MiB]
//   [33554432)  Qb  bf16 [4096][1024]  (pre-scaled by 0.125*log2(e))
//   [41943040)  Kb  bf16 [4096][1024]
//   [50331648)  VTb bf16 [b][h][d][s] = [2][16][64][2048]
//   [58720256)  Ob  bf16 [4096][1024]
//   NOTE: ML aliases wqT/wkT which are DEAD after gemm_qkv completes.

using u16 = unsigned short;
typedef __bf16 bf16x8 __attribute__((ext_vector_type(8)));
typedef short  s16x8  __attribute__((ext_vector_type(8)));
typedef float  f32x4  __attribute__((ext_vector_type(4)));

#define SEQ   2048
#define QSC   0.18033688f   /* 0.125 * log2(e) */

__device__ __forceinline__ u16 to_bf16(float f) {
  return __builtin_bit_cast(u16, (__bf16)f);
}
__device__ __forceinline__ float from_bf16(u16 v) {
  return __builtin_bit_cast(float, ((unsigned)v) << 16);
}
__device__ __forceinline__ bf16x8 frag_cast(s16x8 v) {
  return __builtin_bit_cast(bf16x8, v);
}
__device__ __forceinline__ f32x4 mfma16(bf16x8 a, bf16x8 b, f32x4 c) {
  return __builtin_amdgcn_mfma_f32_16x16x32_bf16(a, b, c, 0, 0, 0);
}
__device__ __forceinline__ void gload_lds16(const void* g, void* l) {
  __builtin_amdgcn_global_load_lds(
      (const __attribute__((address_space(1))) void*)g,
      (__attribute__((address_space(3))) void*)l, 16, 0, 0);
}

// ---------------- weight transpose+convert: w[K][N] f32 -> wT[N][K] bf16 --
__global__ __launch_bounds__(256) void transpose_w(const float* __restrict__ wq,
                                                   const float* __restrict__ wk,
                                                   const float* __restrict__ wv,
                                                   const float* __restrict__ wo,
                                                   u16* __restrict__ wT) {
  __shared__ float tile[32][33];
  const float* src = blockIdx.z == 0 ? wq : blockIdx.z == 1 ? wk
                     : blockIdx.z == 2 ? wv : wo;
  u16* dst = wT + (size_t)blockIdx.z * 1048576;
  const int x0 = blockIdx.x * 32, y0 = blockIdx.y * 32;
  const int tx = threadIdx.x, ty = threadIdx.y;  // block (32,8)
#pragma unroll
  for (int i = 0; i < 4; ++i)
    tile[ty + i * 8][tx] = src[(size_t)(y0 + ty + i * 8) * 1024 + x0 + tx];
  __syncthreads();
#pragma unroll
  for (int i = 0; i < 4; ++i)
    dst[(size_t)(x0 + ty + i * 8) * 1024 + y0 + tx] = to_bf16(tile[tx][ty + i * 8]);
}

// ---------------- fused QKV GEMM + convert, split-K wave-quads ------------
// z=0: Qb = q@wqT^T (scaled); z=1: Kb = k@wkT^T; z=2 swapped: VT = wvT@v^T.
// Quad q = waves 4q..4q+3 accumulates K in [q*512,(q+1)*512) over 16 steps.
// Per-quad LDS As/Bs (16KB each quad); loop body identical to R11 with
// wq = w&3. Exact f32 LDS reduction; quad 0 writes C.
__global__ __launch_bounds__(512) void gemm_qkv(const float* __restrict__ Xq,
                                                const float* __restrict__ Xk,
                                                const float* __restrict__ Xv,
                                                const u16* __restrict__ WT,
                                                u16* __restrict__ Qb,
                                                u16* __restrict__ Kb,
                                                u16* __restrict__ VTb) {
  __shared__ __align__(16) char lds[32768];
  const int z = blockIdx.z;
  const u16* Gbf;      // bf16 operand (gload_lds)
  const float* Gf32;   // f32 operand (reg-staged)
  int row0, n0;
  if (z == 2) {
    Gbf = WT + 2097152;             // A = wvT [1024][1024]
    Gf32 = Xv;                      // B = value rows (seq)
    row0 = blockIdx.y * 128;        // 8 row-blocks
    n0 = blockIdx.x * 128;          // 32 col-blocks
  } else {
    Gf32 = z ? Xk : Xq;             // A = x rows (seq)
    Gbf = WT + (size_t)z * 1048576; // B = wT
    row0 = blockIdx.x * 128;
    n0 = blockIdx.y * 128;
  }
  const int frow0 = (z == 2) ? n0 : row0;   // f32 operand tile base row
  const int wrow0 = (z == 2) ? row0 : n0;   // weight operand tile base row

  const int tid = threadIdx.x;
  const int w = tid >> 6, lane = tid & 63;
  const int quad = w >> 2, wq = w & 3;
  const int g = lane >> 4, c = lane & 15;
  const int wr = wq >> 1, wc = wq & 1;

  char* As = lds + quad * 8192;            // [0,16K): quad A tiles
  char* Bs = lds + 16384 + quad * 8192;    // [16K,32K): quad B tiles
  char* fdst = (z == 2) ? Bs : As;         // f32 operand dest
  char* wdst = (z == 2) ? As : Bs;         // weight operand dest

  f32x4 acc[4][4];
#pragma unroll
  for (int i = 0; i < 4; ++i)
#pragma unroll
    for (int j = 0; j < 4; ++j) acc[i][j] = (f32x4){0.f, 0.f, 0.f, 0.f};

  const int sub = lane >> 2;                       // row within 16-row chunk
  const int kq = lane & 3;                         // k-group slot
  const int ksrc = (kq ^ ((sub >> 1) & 3)) * 8;    // swizzled source k-group
  const int fsw = ((c >> 1) & 3);                  // frag-read swizzle key
  const int kbase = quad * 512;                    // this quad's K origin

  for (int kt = 0; kt < 16; ++kt) {
    const int k0 = kbase + kt * 32;
    s16x8 sreg[2];
#pragma unroll
    for (int it = 0; it < 2; ++it) {
      const int ch = wq * 2 + it;
      const int row = ch * 16 + sub;
      gload_lds16(Gbf + (size_t)(wrow0 + row) * 1024 + k0 + ksrc, wdst + ch * 1024);
      const float4* p = (const float4*)(Gf32 + (size_t)(frow0 + row) * 1024 + k0 + ksrc);
      const float4 aa = p[0], bb = p[1];
      s16x8 o;
      o[0] = (short)to_bf16(aa.x); o[1] = (short)to_bf16(aa.y);
      o[2] = (short)to_bf16(aa.z); o[3] = (short)to_bf16(aa.w);
      o[4] = (short)to_bf16(bb.x); o[5] = (short)to_bf16(bb.y);
      o[6] = (short)to_bf16(bb.z); o[7] = (short)to_bf16(bb.w);
      sreg[it] = o;
    }
#pragma unroll
    for (int it = 0; it < 2; ++it)
      *(s16x8*)(fdst + (wq * 2 + it) * 1024 + lane * 16) = sreg[it];
    __syncthreads();

    bf16x8 af[4], bfr[4];
#pragma unroll
    for (int mi = 0; mi < 4; ++mi)
      af[mi] = frag_cast(*(const s16x8*)(As + (wr * 64 + mi * 16 + c) * 64 + ((g ^ fsw) << 4)));
#pragma unroll
    for (int ni = 0; ni < 4; ++ni)
      bfr[ni] = frag_cast(*(const s16x8*)(Bs + (wc * 64 + ni * 16 + c) * 64 + ((g ^ fsw) << 4)));
#pragma unroll
    for (int mi = 0; mi < 4; ++mi)
#pragma unroll
      for (int ni = 0; ni < 4; ++ni)
        acc[mi][ni] = mfma16(af[mi], bfr[ni], acc[mi][ni]);
    __syncthreads();
  }

  // ---- cross-quad reduction: quad1 -> LDS (element-major), quad0 adds ----
  float* red = (float*)lds;   // 8192 floats = 32KB per pass
#pragma unroll
  for (int pass = 0; pass < 2; ++pass) {
    if (quad == 1) {
#pragma unroll
      for (int mh = 0; mh < 2; ++mh)
#pragma unroll
        for (int ni = 0; ni < 4; ++ni)
#pragma unroll
          for (int r = 0; r < 4; ++r)
            red[(mh * 16 + ni * 4 + r) * 256 + wq * 64 + lane] = acc[pass * 2 + mh][ni][r];
    }
    __syncthreads();
    if (quad == 0) {
#pragma unroll
      for (int mh = 0; mh < 2; ++mh)
#pragma unroll
        for (int ni = 0; ni < 4; ++ni)
#pragma unroll
          for (int r = 0; r < 4; ++r)
            acc[pass * 2 + mh][ni][r] += red[(mh * 16 + ni * 4 + r) * 256 + wq * 64 + lane];
    }
    __syncthreads();
  }

  if (quad != 0) return;
  const float sc = (z == 0) ? QSC : 1.0f;
#pragma unroll
  for (int mi = 0; mi < 4; ++mi) {
    const int rowb = row0 + wr * 64 + mi * 16 + g * 4;
#pragma unroll
    for (int ni = 0; ni < 4; ++ni) {
      const int col = n0 + wc * 64 + ni * 16 + c;
#pragma unroll
      for (int r = 0; r < 4; ++r) {
        const int row = rowb + r;
        const float v = acc[mi][ni][r] * sc;
        if (z == 2) {
          // row = h*64+d, col = b*2048+s
          const int hh = row >> 6, d = row & 63;
          const int bb = col >> 11, s = col & 2047;
          VTb[((size_t)((bb * 16 + hh) * 64 + d)) * 2048 + s] = to_bf16(v);
        } else {
          u16* C = z == 0 ? Qb : Kb;
          C[(size_t)row * 1024 + col] = to_bf16(v);
        }
      }
    }
  }
}

// ---------------- out projection GEMM: BM=64, BN=128, f32 out ------------
__global__ __launch_bounds__(256) void gemm_out(const u16* __restrict__ A,
                                                const u16* __restrict__ BT,
                                                float* __restrict__ C) {
  __shared__ u16 As[64 * 32];
  __shared__ u16 Bs[128 * 32];
  const int tid = threadIdx.x;
  const int w = tid >> 6, lane = tid & 63;
  const int g = lane >> 4, c = lane & 15;
  const int wr = w >> 1, wc = w & 1;
  const int row0 = blockIdx.x * 64;
  const int n0 = blockIdx.y * 128;

  f32x4 acc[2][4];
#pragma unroll
  for (int i = 0; i < 2; ++i)
#pragma unroll
    for (int j = 0; j < 4; ++j) acc[i][j] = (f32x4){0.f, 0.f, 0.f, 0.f};

  const int sub = lane >> 2;
  const int kq = lane & 3;
  const int ksrc = (kq ^ ((sub >> 1) & 3)) * 8;
  const int fsw = ((c >> 1) & 3);

  for (int kt = 0; kt < 32; ++kt) {
    const int k0 = kt * 32;
    {
      const int row = w * 16 + sub;
      gload_lds16(A + (size_t)(row0 + row) * 1024 + k0 + ksrc, (char*)As + w * 1024);
    }
#pragma unroll
    for (int it = 0; it < 2; ++it) {
      const int ch = w * 2 + it;
      const int row = ch * 16 + sub;
      gload_lds16(BT + (size_t)(n0 + row) * 1024 + k0 + ksrc, (char*)Bs + ch * 1024);
    }
    __syncthreads();

    bf16x8 af[2], bfr[4];
#pragma unroll
    for (int mi = 0; mi < 2; ++mi)
      af[mi] = frag_cast(*(const s16x8*)((const char*)As + (wr * 32 + mi * 16 + c) * 64 + ((g ^ fsw) << 4)));
#pragma unroll
    for (int ni = 0; ni < 4; ++ni)
      bfr[ni] = frag_cast(*(const s16x8*)((const char*)Bs + (wc * 64 + ni * 16 + c) * 64 + ((g ^ fsw) << 4)));
#pragma unroll
    for (int mi = 0; mi < 2; ++mi)
#pragma unroll
      for (int ni = 0; ni < 4; ++ni)
        acc[mi][ni] = mfma16(af[mi], bfr[ni], acc[mi][ni]);
    __syncthreads();
  }

#pragma unroll
  for (int mi = 0; mi < 2; ++mi) {
    const int rowb = row0 + wr * 32 + mi * 16 + g * 4;
#pragma unroll
    for (int ni = 0; ni < 4; ++ni) {
      const int col = n0 + wc * 64 + ni * 16 + c;
#pragma unroll
      for (int r = 0; r < 4; ++r)
        C[(size_t)(rowb + r) * 1024 + col] = acc[mi][ni][r];
    }
  }
}

// ---------------- causal flash attention, 8-wave, KVBLK=128 ---------------
// (R8 version verbatim — measured 39.3us.) grid (40, 32) remapped XCD-wise.
// Slice covers <=4 kv tile-pairs (ns=(x+4)>>2; 40 slices/bh). 8 waves x 16
// q-rows. Permuted-K LDS slot (kv&0x63)|((kv&4)<<2)|((kv&0x18)>>1); QK^T
// C-slot (kvf,g,r) holds kv=32(kvf>>1)+4(kvf&1)+8g+r -> PV A-frags packed in
// place. l via ones-MFMA. Writes bf16 partial O + f32 (m,l).
__global__ __launch_bounds__(512, 4) void attn_fwd(const u16* __restrict__ Qb,
                                                   const u16* __restrict__ Kb,
                                                   const u16* __restrict__ VTb,
                                                   u16* __restrict__ PO,
                                                   float* __restrict__ ML) {
  __shared__ u16 Ks[2][128 * 64];   // [buf][slot][d] swizzled   (32 KB)
  __shared__ u16 VTs[2][64 * 128];  // [buf][d][kv] swizzled     (32 KB)

  const int tid = threadIdx.x;
  const int w = tid >> 6, lane = tid & 63;
  const int g = lane >> 4, c = lane & 15;

  // XCD-aware remap: flat -> logical so each XCD gets 4 consecutive bh
  const int flat = blockIdx.x + 40 * blockIdx.y;
  const int logical = (flat & 7) * 160 + (flat >> 3);
  const int slice_id = logical % 40;
  const int bh = logical / 40;
  const int b = bh >> 4, h = bh & 15;

  // decode slice id -> (q-block x, slice sid); ns(x) = (x+4)>>2 over pairs
  int sid = slice_id, x = 0;
  for (; x < 16; ++x) {
    const int ns_ = (x + 4) >> 2;
    if (sid < ns_) break;
    sid -= ns_;
  }
  const int ns = (x + 4) >> 2;
  const int np = x + 1;                       // kv tile-pairs for q-block x
  const int t0 = (sid * np) / ns, t1 = ((sid + 1) * np) / ns;
  const int sg = slice_id + 40 * bh;          // global slice id
  const int q0w = x * 128 + w * 16;           // this wave's first q row

  // Q fragments (B-operand: n=q, k=d) in registers
  bf16x8 qfr[2];
#pragma unroll
  for (int ch = 0; ch < 2; ++ch)
    qfr[ch] = frag_cast(*(const s16x8*)(Qb + (size_t)(b * SEQ + q0w + c) * 1024 + h * 64 + ch * 32 + g * 8));

  s16x8 ones_s;
#pragma unroll
  for (int j = 0; j < 8; ++j) ones_s[j] = (short)0x3F80;  // bf16 1.0
  const bf16x8 onesf = frag_cast(ones_s);

  f32x4 oacc[4];
#pragma unroll
  for (int j = 0; j < 4; ++j) oacc[j] = (f32x4){0.f, 0.f, 0.f, 0.f};
  f32x4 lacc = (f32x4){0.f, 0.f, 0.f, 0.f};
  float m_run = -1e30f;

  // staging geometry
  const int srow = tid >> 3;        // K: 0..63 (+64 on 2nd pass)
  const int scol = (tid & 7) * 8;   // K col elems
  const int vd = tid >> 4;          // V: 0..31 (+32 on 2nd pass)
  const int vcol = (tid & 15) * 8;  // V col elems (kv within pair)

  s16x8 kreg[2], vreg[2];
#define LOADKV(T)                                                                              \
  {                                                                                            \
    const int kv0_ = (T)*128;                                                                  \
    _Pragma("unroll") for (int it = 0; it < 2; ++it) {                                         \
      kreg[it] = *(const s16x8*)(Kb + (size_t)(b * SEQ + kv0_ + srow + it * 64) * 1024 +       \
                                 h * 64 + scol);                                               \
      vreg[it] = *(const s16x8*)(VTb + ((size_t)(bh * 64 + vd + it * 32)) * 2048 + kv0_ +      \
                                 vcol);                                                        \
    }                                                                                          \
  }
#define WRITEKV(BUF)                                                                           \
  {                                                                                            \
    _Pragma("unroll") for (int it = 0; it < 2; ++it) {                                         \
      const int rr_ = srow + it * 64;                                                          \
      const int pr_ = (rr_ & 0x63) | ((rr_ & 4) << 2) | ((rr_ & 0x18) >> 1);                   \
      *(s16x8*)((char*)Ks[BUF] + pr_ * 128 + ((scol * 2) ^ ((pr_ & 7) << 4))) = kreg[it];      \
      const int vr_ = vd + it * 32;                                                            \
      *(s16x8*)((char*)VTs[BUF] + vr_ * 256 + ((vcol * 2) ^ ((vr_ & 7) << 4))) = vreg[it];     \
    }                                                                                          \
  }

  LOADKV(t0);
  WRITEKV(0);
  __syncthreads();

  int cur = 0;
  for (int t = t0; t < t1; ++t) {
    const bool pre = (t + 1 < t1);
    if (pre) LOADKV(t + 1);          // issue early; lands during compute

    const int kv0 = t * 128;
    if (!(kv0 > q0w + 15)) {         // wave has live rows in this pair
      // ---- S^T = K * Q^T over 128 kv: 8 kvf frags
      f32x4 sa[8];
#pragma unroll
      for (int i = 0; i < 8; ++i) sa[i] = (f32x4){0.f, 0.f, 0.f, 0.f};
#pragma unroll
      for (int kvf = 0; kvf < 8; ++kvf) {
        const int kr = kvf * 16 + c;
        const int rb = kr * 128, swz = (kr & 7) << 4;
#pragma unroll
        for (int ch = 0; ch < 2; ++ch) {
          const bf16x8 ak = frag_cast(*(const s16x8*)((char*)Ks[cur] + rb + ((ch * 64 + g * 16) ^ swz)));
          sa[kvf] = mfma16(ak, qfr[ch], sa[kvf]);
        }
      }

      // ---- mask (diagonal pairs only) + tile max
      float mt = -1e30f;
      if (kv0 + 127 > q0w) {         // diagonal pair: mask with permuted kv
        const int q_abs = q0w + c;
#pragma unroll
        for (int kvf = 0; kvf < 8; ++kvf) {
          const int kvb = kv0 + (kvf >> 1) * 32 + (kvf & 1) * 4 + 8 * g;
#pragma unroll
          for (int r = 0; r < 4; ++r) {
            float s = sa[kvf][r];
            if (kvb + r > q_abs) s = -30000.f;
            sa[kvf][r] = s;
            mt = fmaxf(mt, s);
          }
        }
      } else {
#pragma unroll
        for (int kvf = 0; kvf < 8; ++kvf)
#pragma unroll
          for (int r = 0; r < 4; ++r) mt = fmaxf(mt, sa[kvf][r]);
      }
      mt = fmaxf(mt, __shfl_xor(mt, 16));
      mt = fmaxf(mt, __shfl_xor(mt, 32));

      if (__any(mt > m_run + 8.f)) {   // defer-max (T13)
        const float m_new = fmaxf(m_run, mt);
        const float alpha = __builtin_amdgcn_exp2f(m_run - m_new);
        m_run = m_new;
#pragma unroll
        for (int r = 0; r < 4; ++r) {
          const float ar = __shfl(alpha, g * 4 + r);
#pragma unroll
          for (int df = 0; df < 4; ++df) oacc[df][r] *= ar;
          lacc[r] *= ar;
        }
      }

      // ---- exp2 + pack in place into PV A-fragments (4 ch of 32 kv)
      s16x8 pk[4];
#pragma unroll
      for (int kvf = 0; kvf < 8; ++kvf)
#pragma unroll
        for (int r = 0; r < 4; ++r) {
          const float p = __builtin_amdgcn_exp2f(sa[kvf][r] - m_run);
          pk[kvf >> 1][(kvf & 1) * 4 + r] = (short)to_bf16(p);
        }

      // ---- O += P*V ; l += P*1 (row-sum via MFMA, no shfl)
#pragma unroll
      for (int ch = 0; ch < 4; ++ch) {
        const bf16x8 ap = frag_cast(pk[ch]);
#pragma unroll
        for (int df = 0; df < 4; ++df) {
          const int dr = df * 16 + c;
          const bf16x8 bv = frag_cast(*(const s16x8*)((char*)VTs[cur] + dr * 256 +
                                                      ((ch * 64 + g * 16) ^ ((dr & 7) << 4))));
          oacc[df] = mfma16(ap, bv, oacc[df]);
        }
        lacc = mfma16(ap, onesf, lacc);
      }
    }

    if (pre) WRITEKV(cur ^ 1);   // write next buffer (others still read cur)
    __syncthreads();
    cur ^= 1;
  }

  // epilogue: bf16 unnormalized partial O; f32 (m,l)
  const size_t pob = (size_t)sg * 8192;
#pragma unroll
  for (int r = 0; r < 4; ++r) {
    const int row = w * 16 + g * 4 + r;
#pragma unroll
    for (int df = 0; df < 4; ++df)
      PO[pob + row * 64 + df * 16 + c] = to_bf16(oacc[df][r]);
  }
  if (g == 0)
    ML[sg * 256 + (w * 16 + c) * 2 + 0] = m_run;     // m for q=c
  if (c == 0) {
#pragma unroll
    for (int r = 0; r < 4; ++r)
      ML[sg * 256 + (w * 16 + g * 4 + r) * 2 + 1] = lacc[r];  // l for q=4g+r
  }
}

// ---------------- merge split-kv partials -> bf16 Ob ----------------------
// grid (16, 32), 512 thr: x = q-block (128 rows), y = bh. row=tid/4, 16 cols.
__global__ __launch_bounds__(512) void attn_merge(const u16* __restrict__ PO,
                                                  const float* __restrict__ ML,
                                                  u16* __restrict__ Ob) {
  const int x = blockIdx.x, bh = blockIdx.y;
  const int b = bh >> 4, h = bh & 15;
  const int tid = threadIdx.x;
  const int row = tid >> 2, c0 = (tid & 3) << 4;

  int base = 0;
  for (int xp = 0; xp < x; ++xp) base += (xp + 4) >> 2;
  const int ns = (x + 4) >> 2;
  const int sg0 = base + 40 * bh;

  float m[4], l[4], a[4];
  float M = -3e38f;
  for (int i = 0; i < ns; ++i) {
    m[i] = ML[(sg0 + i) * 256 + row * 2 + 0];
    l[i] = ML[(sg0 + i) * 256 + row * 2 + 1];
    M = fmaxf(M, m[i]);
  }
  float denom = 0.f;
  for (int i = 0; i < ns; ++i) {
    a[i] = __builtin_amdgcn_exp2f(m[i] - M);
    denom += a[i] * l[i];
  }
  const float inv = 1.f / denom;

  float o[16];
#pragma unroll
  for (int j = 0; j < 16; ++j) o[j] = 0.f;
  for (int i = 0; i < ns; ++i) {
    const float s = a[i] * inv;
    const u16* p = PO + (size_t)(sg0 + i) * 8192 + row * 64 + c0;
    const s16x8 v0 = *(const s16x8*)p;
    const s16x8 v1 = *(const s16x8*)(p + 8);
#pragma unroll
    for (int j = 0; j < 8; ++j) {
      o[j] += s * from_bf16((u16)v0[j]);
      o[8 + j] += s * from_bf16((u16)v1[j]);
    }
  }

  s16x8 lo, hi;
#pragma unroll
  for (int j = 0; j < 8; ++j) {
    lo[j] = (short)to_bf16(o[j]);
    hi[j] = (short)to_bf16(o[8 + j]);
  }
  u16* dst = Ob + (size_t)(b * SEQ + x * 128 + row) * 1024 + h * 64 + c0;
  *(s16x8*)dst = lo;
  *(s16x8*)(dst + 8) = hi;
}

// --------------------------------------------------------------------------
extern "C" void kernel_launch(void* const* d_in, const int* in_sizes, int n_in,
                              void* d_out, int out_size, void* d_ws, size_t ws_size,
                              hipStream_t stream) {
  const float* query = (const float*)d_in[0];
  const float* key_ = (const float*)d_in[1];
  const float* value = (const float*)d_in[2];
  const float* w_q = (const float*)d_in[3];
  const float* w_k = (const float*)d_in[4];
  const float* w_v = (const float*)d_in[5];
  const float* w_o = (const float*)d_in[6];

  char* ws = (char*)d_ws;
  u16* PO = (u16*)(ws + 0);
  u16* wT = (u16*)(ws + 25165824);
  float* ML = (float*)(ws + 25165824);   // aliases wqT/wkT (dead post-qkv)
  u16* Qb = (u16*)(ws + 33554432);
  u16* Kb = (u16*)(ws + 41943040);
  u16* VTb = (u16*)(ws + 50331648);
  u16* Ob = (u16*)(ws + 58720256);

  transpose_w<<<dim3(32, 32, 4), dim3(32, 8), 0, stream>>>(w_q, w_k, w_v, w_o, wT);
  gemm_qkv<<<dim3(32, 8, 3), 512, 0, stream>>>(query, key_, value, wT, Qb, Kb, VTb);
  attn_fwd<<<dim3(40, 32), 512, 0, stream>>>(Qb, Kb, VTb, PO, ML);
  attn_merge<<<dim3(16, 32), 512, 0, stream>>>(PO, ML, Ob);
  gemm_out<<<dim3(64, 8), 256, 0, stream>>>(Ob, wT + 3145728, (float*)d_out);
}

// Round 18
// 110.843 us; speedup vs baseline: 1.9792x; 1.0792x over previous
//
#include <hip/hip_runtime.h>

// MultiHeadAttention: x@Wq/Wk/Wv -> causal flash attn -> @Wo
// B=2 S=2048 H=16 D=64 HIDDEN=1024. All MFMA bf16 16x16x32, f32 accum.
//
// R17 = R11 (best measured: 111.4us) + XCD-aware grid swizzle on the GEMMs:
//  - gemm_qkv: flat 768-block grid, f = bx%8 + 8*(by + 8*(bx/8 + 4*z)) so
//    xcd(f)=f%8=bx%8 -> the 8 blocks sharing one 512KB f32 x-tile co-reside
//    on ONE XCD's L2 (384MB of L3 re-reads -> L2 hits). Same T1 lever that
//    cut attn FETCH 80->12MB in R7. Kernel body unchanged from R11.
//  - gemm_out: same remap (Ob tiles re-read 8x).
//  - R16 split-K / R15 BK64 / R14 BM64 / R12 dbuf all REVERTED (measured
//    regressions; R11 qkv body is the verified optimum).
//
// Workspace map (64 MiB), with region reuse:
//   [0)         PO bf16 partial O: 1280 slices x 128 rows x 64 d (21 MiB)
//   [25165824)  ML f32: 1280 slices x 128 rows x {m,l}  (1.31 MiB)
//   [31457280)  woT (live until gemm_out)   [wT block: 25165824 + z*2MiB]
//   [33554432)  Qb  bf16 [4096][1024]  (pre-scaled by 0.125*log2(e))
//   [41943040)  Kb  bf16 [4096][1024]
//   [50331648)  VTb bf16 [b][h][d][s] = [2][16][64][2048]
//   [58720256)  Ob  bf16 [4096][1024]
//   NOTE: ML aliases wqT/wkT which are DEAD after gemm_qkv completes.

using u16 = unsigned short;
typedef __bf16 bf16x8 __attribute__((ext_vector_type(8)));
typedef short  s16x8  __attribute__((ext_vector_type(8)));
typedef float  f32x4  __attribute__((ext_vector_type(4)));

#define SEQ   2048
#define QSC   0.18033688f   /* 0.125 * log2(e) */

__device__ __forceinline__ u16 to_bf16(float f) {
  return __builtin_bit_cast(u16, (__bf16)f);
}
__device__ __forceinline__ float from_bf16(u16 v) {
  return __builtin_bit_cast(float, ((unsigned)v) << 16);
}
__device__ __forceinline__ bf16x8 frag_cast(s16x8 v) {
  return __builtin_bit_cast(bf16x8, v);
}
__device__ __forceinline__ f32x4 mfma16(bf16x8 a, bf16x8 b, f32x4 c) {
  return __builtin_amdgcn_mfma_f32_16x16x32_bf16(a, b, c, 0, 0, 0);
}
__device__ __forceinline__ void gload_lds16(const void* g, void* l) {
  __builtin_amdgcn_global_load_lds(
      (const __attribute__((address_space(1))) void*)g,
      (__attribute__((address_space(3))) void*)l, 16, 0, 0);
}

// ---------------- weight transpose+convert: w[K][N] f32 -> wT[N][K] bf16 --
__global__ __launch_bounds__(256) void transpose_w(const float* __restrict__ wq,
                                                   const float* __restrict__ wk,
                                                   const float* __restrict__ wv,
                                                   const float* __restrict__ wo,
                                                   u16* __restrict__ wT) {
  __shared__ float tile[32][33];
  const float* src = blockIdx.z == 0 ? wq : blockIdx.z == 1 ? wk
                     : blockIdx.z == 2 ? wv : wo;
  u16* dst = wT + (size_t)blockIdx.z * 1048576;
  const int x0 = blockIdx.x * 32, y0 = blockIdx.y * 32;
  const int tx = threadIdx.x, ty = threadIdx.y;  // block (32,8)
#pragma unroll
  for (int i = 0; i < 4; ++i)
    tile[ty + i * 8][tx] = src[(size_t)(y0 + ty + i * 8) * 1024 + x0 + tx];
  __syncthreads();
#pragma unroll
  for (int i = 0; i < 4; ++i)
    dst[(size_t)(x0 + ty + i * 8) * 1024 + y0 + tx] = to_bf16(tile[tx][ty + i * 8]);
}

// ---------------- fused QKV GEMM + f32->bf16 convert (R11 body) ----------
// z=0: Qb = q@wqT^T (scaled); z=1: Kb = k@wkT^T; z=2 swapped: VT = wvT@v^T.
// Flat 768-block grid, XCD-swizzled: f = bx%8 + 8*(by + 8*(bx/8 + 4*z)).
// xcd(f)=f%8=bx%8 -> 8 blocks sharing an f32 x-tile co-reside on one XCD.
__global__ __launch_bounds__(256) void gemm_qkv(const float* __restrict__ Xq,
                                                const float* __restrict__ Xk,
                                                const float* __restrict__ Xv,
                                                const u16* __restrict__ WT,
                                                u16* __restrict__ Qb,
                                                u16* __restrict__ Kb,
                                                u16* __restrict__ VTb) {
  __shared__ u16 As[128 * 32];
  __shared__ u16 Bs[128 * 32];
  // decode XCD-swizzled flat id
  const int f = blockIdx.x;
  const int bxm = f & 7, r1 = f >> 3;
  const int by = r1 & 7, r2 = r1 >> 3;
  const int bxd = r2 & 3, z = r2 >> 2;
  const int bx = bxm + 8 * bxd;            // 0..31

  const u16* Gbf;      // bf16 operand (gload_lds)
  const float* Gf32;   // f32 operand (reg-staged)
  int row0, n0;
  if (z == 2) {
    Gbf = WT + 2097152;             // A = wvT [1024][1024]
    Gf32 = Xv;                      // B = value rows (seq)
    row0 = by * 128;                // 8 row-blocks over 1024
    n0 = bx * 128;                  // 32 col-blocks over 4096
  } else {
    Gf32 = z ? Xk : Xq;             // A = x rows (seq)
    Gbf = WT + (size_t)z * 1048576; // B = wT
    row0 = bx * 128;                // 32 row-blocks over 4096
    n0 = by * 128;                  // 8 col-blocks over 1024
  }
  const int frow0 = (z == 2) ? n0 : row0;   // f32 operand tile base row
  const int wrow0 = (z == 2) ? row0 : n0;   // weight operand tile base row

  const int tid = threadIdx.x;
  const int w = tid >> 6, lane = tid & 63;
  const int g = lane >> 4, c = lane & 15;
  const int wr = w >> 1, wc = w & 1;

  f32x4 acc[4][4];
#pragma unroll
  for (int i = 0; i < 4; ++i)
#pragma unroll
    for (int j = 0; j < 4; ++j) acc[i][j] = (f32x4){0.f, 0.f, 0.f, 0.f};

  const int sub = lane >> 2;                       // row within 16-row chunk
  const int kq = lane & 3;                         // k-group slot
  const int ksrc = (kq ^ ((sub >> 1) & 3)) * 8;    // swizzled source k-group
  const int fsw = ((c >> 1) & 3);                  // frag-read swizzle key

  char* fdst = (z == 2) ? (char*)Bs : (char*)As;   // f32 operand dest
  char* wdst = (z == 2) ? (char*)As : (char*)Bs;   // weight operand dest

  for (int kt = 0; kt < 32; ++kt) {
    const int k0 = kt * 32;
    s16x8 sreg[2];
#pragma unroll
    for (int it = 0; it < 2; ++it) {
      const int ch = w * 2 + it;
      const int row = ch * 16 + sub;
      gload_lds16(Gbf + (size_t)(wrow0 + row) * 1024 + k0 + ksrc, wdst + ch * 1024);
      const float4* p = (const float4*)(Gf32 + (size_t)(frow0 + row) * 1024 + k0 + ksrc);
      const float4 aa = p[0], bb = p[1];
      s16x8 o;
      o[0] = (short)to_bf16(aa.x); o[1] = (short)to_bf16(aa.y);
      o[2] = (short)to_bf16(aa.z); o[3] = (short)to_bf16(aa.w);
      o[4] = (short)to_bf16(bb.x); o[5] = (short)to_bf16(bb.y);
      o[6] = (short)to_bf16(bb.z); o[7] = (short)to_bf16(bb.w);
      sreg[it] = o;
    }
#pragma unroll
    for (int it = 0; it < 2; ++it)
      *(s16x8*)(fdst + (w * 2 + it) * 1024 + lane * 16) = sreg[it];
    __syncthreads();

    bf16x8 af[4], bfr[4];
#pragma unroll
    for (int mi = 0; mi < 4; ++mi)
      af[mi] = frag_cast(*(const s16x8*)((const char*)As + (wr * 64 + mi * 16 + c) * 64 + ((g ^ fsw) << 4)));
#pragma unroll
    for (int ni = 0; ni < 4; ++ni)
      bfr[ni] = frag_cast(*(const s16x8*)((const char*)Bs + (wc * 64 + ni * 16 + c) * 64 + ((g ^ fsw) << 4)));
#pragma unroll
    for (int mi = 0; mi < 4; ++mi)
#pragma unroll
      for (int ni = 0; ni < 4; ++ni)
        acc[mi][ni] = mfma16(af[mi], bfr[ni], acc[mi][ni]);
    __syncthreads();
  }

  const float sc = (z == 0) ? QSC : 1.0f;
#pragma unroll
  for (int mi = 0; mi < 4; ++mi) {
    const int rowb = row0 + wr * 64 + mi * 16 + g * 4;
#pragma unroll
    for (int ni = 0; ni < 4; ++ni) {
      const int col = n0 + wc * 64 + ni * 16 + c;
#pragma unroll
      for (int r = 0; r < 4; ++r) {
        const int row = rowb + r;
        const float v = acc[mi][ni][r] * sc;
        if (z == 2) {
          // row = h*64+d, col = b*2048+s
          const int hh = row >> 6, d = row & 63;
          const int bb = col >> 11, s = col & 2047;
          VTb[((size_t)((bb * 16 + hh) * 64 + d)) * 2048 + s] = to_bf16(v);
        } else {
          u16* C = z == 0 ? Qb : Kb;
          C[(size_t)row * 1024 + col] = to_bf16(v);
        }
      }
    }
  }
}

// ---------------- out projection GEMM: BM=64, BN=128, f32 out ------------
// Flat 512-block grid, XCD-swizzled: f = bx%8 + 8*(by + 8*(bx/8)).
__global__ __launch_bounds__(256) void gemm_out(const u16* __restrict__ A,
                                                const u16* __restrict__ BT,
                                                float* __restrict__ C) {
  __shared__ u16 As[64 * 32];
  __shared__ u16 Bs[128 * 32];
  const int f = blockIdx.x;
  const int bxm = f & 7, r1 = f >> 3;
  const int by = r1 & 7, bxd = r1 >> 3;    // bxd 0..7
  const int bx = bxm + 8 * bxd;            // 0..63
  const int row0 = bx * 64;
  const int n0 = by * 128;

  const int tid = threadIdx.x;
  const int w = tid >> 6, lane = tid & 63;
  const int g = lane >> 4, c = lane & 15;
  const int wr = w >> 1, wc = w & 1;

  f32x4 acc[2][4];
#pragma unroll
  for (int i = 0; i < 2; ++i)
#pragma unroll
    for (int j = 0; j < 4; ++j) acc[i][j] = (f32x4){0.f, 0.f, 0.f, 0.f};

  const int sub = lane >> 2;
  const int kq = lane & 3;
  const int ksrc = (kq ^ ((sub >> 1) & 3)) * 8;
  const int fsw = ((c >> 1) & 3);

  for (int kt = 0; kt < 32; ++kt) {
    const int k0 = kt * 32;
    {
      const int row = w * 16 + sub;
      gload_lds16(A + (size_t)(row0 + row) * 1024 + k0 + ksrc, (char*)As + w * 1024);
    }
#pragma unroll
    for (int it = 0; it < 2; ++it) {
      const int ch = w * 2 + it;
      const int row = ch * 16 + sub;
      gload_lds16(BT + (size_t)(n0 + row) * 1024 + k0 + ksrc, (char*)Bs + ch * 1024);
    }
    __syncthreads();

    bf16x8 af[2], bfr[4];
#pragma unroll
    for (int mi = 0; mi < 2; ++mi)
      af[mi] = frag_cast(*(const s16x8*)((const char*)As + (wr * 32 + mi * 16 + c) * 64 + ((g ^ fsw) << 4)));
#pragma unroll
    for (int ni = 0; ni < 4; ++ni)
      bfr[ni] = frag_cast(*(const s16x8*)((const char*)Bs + (wc * 64 + ni * 16 + c) * 64 + ((g ^ fsw) << 4)));
#pragma unroll
    for (int mi = 0; mi < 2; ++mi)
#pragma unroll
      for (int ni = 0; ni < 4; ++ni)
        acc[mi][ni] = mfma16(af[mi], bfr[ni], acc[mi][ni]);
    __syncthreads();
  }

#pragma unroll
  for (int mi = 0; mi < 2; ++mi) {
    const int rowb = row0 + wr * 32 + mi * 16 + g * 4;
#pragma unroll
    for (int ni = 0; ni < 4; ++ni) {
      const int col = n0 + wc * 64 + ni * 16 + c;
#pragma unroll
      for (int r = 0; r < 4; ++r)
        C[(size_t)(rowb + r) * 1024 + col] = acc[mi][ni][r];
    }
  }
}

// ---------------- causal flash attention, 8-wave, KVBLK=128 ---------------
// (R8 version verbatim — measured 39.3us.) grid (40, 32) remapped XCD-wise.
// Slice covers <=4 kv tile-pairs (ns=(x+4)>>2; 40 slices/bh). 8 waves x 16
// q-rows. Permuted-K LDS slot (kv&0x63)|((kv&4)<<2)|((kv&0x18)>>1); QK^T
// C-slot (kvf,g,r) holds kv=32(kvf>>1)+4(kvf&1)+8g+r -> PV A-frags packed in
// place. l via ones-MFMA. Writes bf16 partial O + f32 (m,l).
__global__ __launch_bounds__(512, 4) void attn_fwd(const u16* __restrict__ Qb,
                                                   const u16* __restrict__ Kb,
                                                   const u16* __restrict__ VTb,
                                                   u16* __restrict__ PO,
                                                   float* __restrict__ ML) {
  __shared__ u16 Ks[2][128 * 64];   // [buf][slot][d] swizzled   (32 KB)
  __shared__ u16 VTs[2][64 * 128];  // [buf][d][kv] swizzled     (32 KB)

  const int tid = threadIdx.x;
  const int w = tid >> 6, lane = tid & 63;
  const int g = lane >> 4, c = lane & 15;

  // XCD-aware remap: flat -> logical so each XCD gets 4 consecutive bh
  const int flat = blockIdx.x + 40 * blockIdx.y;
  const int logical = (flat & 7) * 160 + (flat >> 3);
  const int slice_id = logical % 40;
  const int bh = logical / 40;
  const int b = bh >> 4, h = bh & 15;

  // decode slice id -> (q-block x, slice sid); ns(x) = (x+4)>>2 over pairs
  int sid = slice_id, x = 0;
  for (; x < 16; ++x) {
    const int ns_ = (x + 4) >> 2;
    if (sid < ns_) break;
    sid -= ns_;
  }
  const int ns = (x + 4) >> 2;
  const int np = x + 1;                       // kv tile-pairs for q-block x
  const int t0 = (sid * np) / ns, t1 = ((sid + 1) * np) / ns;
  const int sg = slice_id + 40 * bh;          // global slice id
  const int q0w = x * 128 + w * 16;           // this wave's first q row

  // Q fragments (B-operand: n=q, k=d) in registers
  bf16x8 qfr[2];
#pragma unroll
  for (int ch = 0; ch < 2; ++ch)
    qfr[ch] = frag_cast(*(const s16x8*)(Qb + (size_t)(b * SEQ + q0w + c) * 1024 + h * 64 + ch * 32 + g * 8));

  s16x8 ones_s;
#pragma unroll
  for (int j = 0; j < 8; ++j) ones_s[j] = (short)0x3F80;  // bf16 1.0
  const bf16x8 onesf = frag_cast(ones_s);

  f32x4 oacc[4];
#pragma unroll
  for (int j = 0; j < 4; ++j) oacc[j] = (f32x4){0.f, 0.f, 0.f, 0.f};
  f32x4 lacc = (f32x4){0.f, 0.f, 0.f, 0.f};
  float m_run = -1e30f;

  // staging geometry
  const int srow = tid >> 3;        // K: 0..63 (+64 on 2nd pass)
  const int scol = (tid & 7) * 8;   // K col elems
  const int vd = tid >> 4;          // V: 0..31 (+32 on 2nd pass)
  const int vcol = (tid & 15) * 8;  // V col elems (kv within pair)

  s16x8 kreg[2], vreg[2];
#define LOADKV(T)                                                                              \
  {                                                                                            \
    const int kv0_ = (T)*128;                                                                  \
    _Pragma("unroll") for (int it = 0; it < 2; ++it) {                                         \
      kreg[it] = *(const s16x8*)(Kb + (size_t)(b * SEQ + kv0_ + srow + it * 64) * 1024 +       \
                                 h * 64 + scol);                                               \
      vreg[it] = *(const s16x8*)(VTb + ((size_t)(bh * 64 + vd + it * 32)) * 2048 + kv0_ +      \
                                 vcol);                                                        \
    }                                                                                          \
  }
#define WRITEKV(BUF)                                                                           \
  {                                                                                            \
    _Pragma("unroll") for (int it = 0; it < 2; ++it) {                                         \
      const int rr_ = srow + it * 64;                                                          \
      const int pr_ = (rr_ & 0x63) | ((rr_ & 4) << 2) | ((rr_ & 0x18) >> 1);                   \
      *(s16x8*)((char*)Ks[BUF] + pr_ * 128 + ((scol * 2) ^ ((pr_ & 7) << 4))) = kreg[it];      \
      const int vr_ = vd + it * 32;                                                            \
      *(s16x8*)((char*)VTs[BUF] + vr_ * 256 + ((vcol * 2) ^ ((vr_ & 7) << 4))) = vreg[it];     \
    }                                                                                          \
  }

  LOADKV(t0);
  WRITEKV(0);
  __syncthreads();

  int cur = 0;
  for (int t = t0; t < t1; ++t) {
    const bool pre = (t + 1 < t1);
    if (pre) LOADKV(t + 1);          // issue early; lands during compute

    const int kv0 = t * 128;
    if (!(kv0 > q0w + 15)) {         // wave has live rows in this pair
      // ---- S^T = K * Q^T over 128 kv: 8 kvf frags
      f32x4 sa[8];
#pragma unroll
      for (int i = 0; i < 8; ++i) sa[i] = (f32x4){0.f, 0.f, 0.f, 0.f};
#pragma unroll
      for (int kvf = 0; kvf < 8; ++kvf) {
        const int kr = kvf * 16 + c;
        const int rb = kr * 128, swz = (kr & 7) << 4;
#pragma unroll
        for (int ch = 0; ch < 2; ++ch) {
          const bf16x8 ak = frag_cast(*(const s16x8*)((char*)Ks[cur] + rb + ((ch * 64 + g * 16) ^ swz)));
          sa[kvf] = mfma16(ak, qfr[ch], sa[kvf]);
        }
      }

      // ---- mask (diagonal pairs only) + tile max
      float mt = -1e30f;
      if (kv0 + 127 > q0w) {         // diagonal pair: mask with permuted kv
        const int q_abs = q0w + c;
#pragma unroll
        for (int kvf = 0; kvf < 8; ++kvf) {
          const int kvb = kv0 + (kvf >> 1) * 32 + (kvf & 1) * 4 + 8 * g;
#pragma unroll
          for (int r = 0; r < 4; ++r) {
            float s = sa[kvf][r];
            if (kvb + r > q_abs) s = -30000.f;
            sa[kvf][r] = s;
            mt = fmaxf(mt, s);
          }
        }
      } else {
#pragma unroll
        for (int kvf = 0; kvf < 8; ++kvf)
#pragma unroll
          for (int r = 0; r < 4; ++r) mt = fmaxf(mt, sa[kvf][r]);
      }
      mt = fmaxf(mt, __shfl_xor(mt, 16));
      mt = fmaxf(mt, __shfl_xor(mt, 32));

      if (__any(mt > m_run + 8.f)) {   // defer-max (T13)
        const float m_new = fmaxf(m_run, mt);
        const float alpha = __builtin_amdgcn_exp2f(m_run - m_new);
        m_run = m_new;
#pragma unroll
        for (int r = 0; r < 4; ++r) {
          const float ar = __shfl(alpha, g * 4 + r);
#pragma unroll
          for (int df = 0; df < 4; ++df) oacc[df][r] *= ar;
          lacc[r] *= ar;
        }
      }

      // ---- exp2 + pack in place into PV A-fragments (4 ch of 32 kv)
      s16x8 pk[4];
#pragma unroll
      for (int kvf = 0; kvf < 8; ++kvf)
#pragma unroll
        for (int r = 0; r < 4; ++r) {
          const float p = __builtin_amdgcn_exp2f(sa[kvf][r] - m_run);
          pk[kvf >> 1][(kvf & 1) * 4 + r] = (short)to_bf16(p);
        }

      // ---- O += P*V ; l += P*1 (row-sum via MFMA, no shfl)
#pragma unroll
      for (int ch = 0; ch < 4; ++ch) {
        const bf16x8 ap = frag_cast(pk[ch]);
#pragma unroll
        for (int df = 0; df < 4; ++df) {
          const int dr = df * 16 + c;
          const bf16x8 bv = frag_cast(*(const s16x8*)((char*)VTs[cur] + dr * 256 +
                                                      ((ch * 64 + g * 16) ^ ((dr & 7) << 4))));
          oacc[df] = mfma16(ap, bv, oacc[df]);
        }
        lacc = mfma16(ap, onesf, lacc);
      }
    }

    if (pre) WRITEKV(cur ^ 1);   // write next buffer (others still read cur)
    __syncthreads();
    cur ^= 1;
  }

  // epilogue: bf16 unnormalized partial O; f32 (m,l)
  const size_t pob = (size_t)sg * 8192;
#pragma unroll
  for (int r = 0; r < 4; ++r) {
    const int row = w * 16 + g * 4 + r;
#pragma unroll
    for (int df = 0; df < 4; ++df)
      PO[pob + row * 64 + df * 16 + c] = to_bf16(oacc[df][r]);
  }
  if (g == 0)
    ML[sg * 256 + (w * 16 + c) * 2 + 0] = m_run;     // m for q=c
  if (c == 0) {
#pragma unroll
    for (int r = 0; r < 4; ++r)
      ML[sg * 256 + (w * 16 + g * 4 + r) * 2 + 1] = lacc[r];  // l for q=4g+r
  }
}

// ---------------- merge split-kv partials -> bf16 Ob ----------------------
// grid (16, 32), 512 thr: x = q-block (128 rows), y = bh. row=tid/4, 16 cols.
__global__ __launch_bounds__(512) void attn_merge(const u16* __restrict__ PO,
                                                  const float* __restrict__ ML,
                                                  u16* __restrict__ Ob) {
  const int x = blockIdx.x, bh = blockIdx.y;
  const int b = bh >> 4, h = bh & 15;
  const int tid = threadIdx.x;
  const int row = tid >> 2, c0 = (tid & 3) << 4;

  int base = 0;
  for (int xp = 0; xp < x; ++xp) base += (xp + 4) >> 2;
  const int ns = (x + 4) >> 2;
  const int sg0 = base + 40 * bh;

  float m[4], l[4], a[4];
  float M = -3e38f;
  for (int i = 0; i < ns; ++i) {
    m[i] = ML[(sg0 + i) * 256 + row * 2 + 0];
    l[i] = ML[(sg0 + i) * 256 + row * 2 + 1];
    M = fmaxf(M, m[i]);
  }
  float denom = 0.f;
  for (int i = 0; i < ns; ++i) {
    a[i] = __builtin_amdgcn_exp2f(m[i] - M);
    denom += a[i] * l[i];
  }
  const float inv = 1.f / denom;

  float o[16];
#pragma unroll
  for (int j = 0; j < 16; ++j) o[j] = 0.f;
  for (int i = 0; i < ns; ++i) {
    const float s = a[i] * inv;
    const u16* p = PO + (size_t)(sg0 + i) * 8192 + row * 64 + c0;
    const s16x8 v0 = *(const s16x8*)p;
    const s16x8 v1 = *(const s16x8*)(p + 8);
#pragma unroll
    for (int j = 0; j < 8; ++j) {
      o[j] += s * from_bf16((u16)v0[j]);
      o[8 + j] += s * from_bf16((u16)v1[j]);
    }
  }

  s16x8 lo, hi;
#pragma unroll
  for (int j = 0; j < 8; ++j) {
    lo[j] = (short)to_bf16(o[j]);
    hi[j] = (short)to_bf16(o[8 + j]);
  }
  u16* dst = Ob + (size_t)(b * SEQ + x * 128 + row) * 1024 + h * 64 + c0;
  *(s16x8*)dst = lo;
  *(s16x8*)(dst + 8) = hi;
}

// --------------------------------------------------------------------------
extern "C" void kernel_launch(void* const* d_in, const int* in_sizes, int n_in,
                              void* d_out, int out_size, void* d_ws, size_t ws_size,
                              hipStream_t stream) {
  const float* query = (const float*)d_in[0];
  const float* key_ = (const float*)d_in[1];
  const float* value = (const float*)d_in[2];
  const float* w_q = (const float*)d_in[3];
  const float* w_k = (const float*)d_in[4];
  const float* w_v = (const float*)d_in[5];
  const float* w_o = (const float*)d_in[6];

  char* ws = (char*)d_ws;
  u16* PO = (u16*)(ws + 0);
  u16* wT = (u16*)(ws + 25165824);
  float* ML = (float*)(ws + 25165824);   // aliases wqT/wkT (dead post-qkv)
  u16* Qb = (u16*)(ws + 33554432);
  u16* Kb = (u16*)(ws + 41943040);
  u16* VTb = (u16*)(ws + 50331648);
  u16* Ob = (u16*)(ws + 58720256);

  transpose_w<<<dim3(32, 32, 4), dim3(32, 8), 0, stream>>>(w_q, w_k, w_v, w_o, wT);
  gemm_qkv<<<dim3(768), 256, 0, stream>>>(query, key_, value, wT, Qb, Kb, VTb);
  attn_fwd<<<dim3(40, 32), 512, 0, stream>>>(Qb, Kb, VTb, PO, ML);
  attn_merge<<<dim3(16, 32), 512, 0, stream>>>(PO, ML, Ob);
  gemm_out<<<dim3(512), 256, 0, stream>>>(Ob, wT + 3145728, (float*)d_out);
}